// Round 1
// baseline (2440.026 us; speedup 1.0000x reference)
//
#include <hip/hip_runtime.h>
#include <math.h>

constexpr int Bn = 32, Ln = 2048, IN_DIM = 182, OUT_DIM = 2;
constexpr int Hn = 256, N2n = 32, NLn = 4;
constexpr int Tn = 128, NCn = Ln / Tn;  // 16 chunks of 128 steps

// ---------------- per-layer constants: a = exp(dt*A), a^T, C' = 2*C*(a-1)/A ----
__global__ void k_consts(const float* __restrict__ C2, const float* __restrict__ log_dt,
                         const float* __restrict__ log_A_real, const float* __restrict__ A_imag,
                         float* __restrict__ cA, float* __restrict__ cAT, float* __restrict__ cC) {
  int idx = blockIdx.x * blockDim.x + threadIdx.x;  // l*H*N2 + h*N2 + n
  if (idx >= NLn * Hn * N2n) return;
  int lh = idx / N2n;
  int h = lh % Hn;
  int l = lh / Hn;
  float dt = expf(log_dt[l * Hn + h]);
  float Ar = -expf(log_A_real[idx]);
  float Ai = A_imag[idx];
  float dr = Ar * dt, di = Ai * dt;
  float ea = expf(dr);
  float ar = ea * cosf(di), ai = ea * sinf(di);
  float eT = expf(dr * (float)Tn);
  float aTr = eT * cosf(di * (float)Tn), aTi = eT * sinf(di * (float)Tn);
  float nr = ar - 1.0f, ni = ai;                      // exp(dtA) - 1
  float inv = 1.0f / (Ar * Ar + Ai * Ai);
  float qr = (nr * Ar + ni * Ai) * inv;               // (a-1)/A
  float qi = (ni * Ar - nr * Ai) * inv;
  float c2r = C2[idx * 2 + 0], c2i = C2[idx * 2 + 1];
  cA[idx * 2 + 0] = ar;   cA[idx * 2 + 1] = ai;
  cAT[idx * 2 + 0] = aTr; cAT[idx * 2 + 1] = aTi;
  cC[idx * 2 + 0] = 2.0f * (c2r * qr - c2i * qi);     // fold the 2x of 2*Re(...)
  cC[idx * 2 + 1] = 2.0f * (c2r * qi + c2i * qr);
}

// ---------------- transpose Wglu (l,o,k) -> Wgt (l,k,o) so weight loads coalesce over o
__global__ void k_wgt(const float* __restrict__ Wglu, float* __restrict__ Wgt) {
  int idx = blockIdx.x * blockDim.x + threadIdx.x;
  if (idx >= NLn * 2 * Hn * Hn) return;
  int k = idx % Hn;
  int rest = idx / Hn;
  int o = rest % (2 * Hn);
  int l = rest / (2 * Hn);
  Wgt[(size_t)(l * Hn + k) * (2 * Hn) + o] = Wglu[idx];
}

// ---------------- input projection: (B*L,182) @ (182,256) + b -> X (B,L,H) -----
constexpr int ROWS_IP = 32;
__global__ __launch_bounds__(256) void k_inproj(const float* __restrict__ nin,
                                                const float* __restrict__ Win,
                                                const float* __restrict__ b_in,
                                                float* __restrict__ X) {
  __shared__ __align__(16) float at[ROWS_IP * IN_DIM];  // 23.3 KB
  int m0 = blockIdx.x * ROWS_IP;
  int h = threadIdx.x;
  for (int i = h; i < ROWS_IP * IN_DIM; i += 256) at[i] = nin[(size_t)m0 * IN_DIM + i];
  __syncthreads();
  float acc[ROWS_IP];
#pragma unroll
  for (int r = 0; r < ROWS_IP; r++) acc[r] = 0.0f;
  for (int k = 0; k < IN_DIM; k += 2) {
    float w0 = Win[k * Hn + h];
    float w1 = Win[(k + 1) * Hn + h];
#pragma unroll
    for (int r = 0; r < ROWS_IP; r++) {
      acc[r] = fmaf(at[r * IN_DIM + k], w0, acc[r]);
      acc[r] = fmaf(at[r * IN_DIM + k + 1], w1, acc[r]);
    }
  }
  float bb = b_in[h];
#pragma unroll
  for (int r = 0; r < ROWS_IP; r++) X[(size_t)(m0 + r) * Hn + h] = acc[r] + bb;
}

// ---------------- scan kernel A: per-chunk local end-state (zero init) ---------
// S layout: [b][c][n][h] of float2 -> all accesses lane-coalesced
__global__ __launch_bounds__(256) void k_scanA(const float* __restrict__ X,
                                               const float* __restrict__ cA,
                                               float* __restrict__ S, int layer) {
  int h = threadIdx.x;
  int c = blockIdx.x;
  int b = blockIdx.y;
  const float2* a2 = (const float2*)(cA + (size_t)((layer * Hn + h) * N2n) * 2);
  float ar[N2n], ai[N2n], sr[N2n], si[N2n];
#pragma unroll
  for (int n = 0; n < N2n; n++) {
    float2 v = a2[n];
    ar[n] = v.x; ai[n] = v.y; sr[n] = 0.0f; si[n] = 0.0f;
  }
  const float* xp = X + (size_t)(b * Ln + c * Tn) * Hn + h;
  float u = xp[0];
  for (int t = 0; t < Tn; t++) {
    float unext = xp[(t + 1) * Hn];  // last read spills into next ws buffer: valid mem, unused
#pragma unroll
    for (int n = 0; n < N2n; n++) {
      float tr = fmaf(ar[n], sr[n], u);
      tr = fmaf(-ai[n], si[n], tr);
      float ti = ar[n] * si[n];
      ti = fmaf(ai[n], sr[n], ti);
      sr[n] = tr; si[n] = ti;
    }
    u = unext;
  }
  float2* sp = (float2*)S + ((size_t)(b * NCn + c) * N2n) * Hn + h;
#pragma unroll
  for (int n = 0; n < N2n; n++) sp[(size_t)n * Hn] = make_float2(sr[n], si[n]);
}

// ---------------- scan kernel B: carry scan across chunks (in place) -----------
__global__ void k_scanB(float* __restrict__ S, const float* __restrict__ cAT, int layer) {
  int idx = blockIdx.x * blockDim.x + threadIdx.x;  // b*(N2*H) + n*H + h
  if (idx >= Bn * Hn * N2n) return;
  int h = idx % Hn;
  int n = (idx / Hn) % N2n;
  int b = idx / (Hn * N2n);
  const float2 aT = *(const float2*)(cAT + (size_t)((layer * Hn + h) * N2n + n) * 2);
  float cr = 0.0f, ci = 0.0f;
  for (int c = 0; c < NCn; c++) {
    float2* sp = (float2*)S + ((size_t)(b * NCn + c) * N2n + n) * Hn + h;
    float2 sl = *sp;
    *sp = make_float2(cr, ci);  // store carry-in for this chunk
    float nr = fmaf(aT.x, cr, sl.x);
    nr = fmaf(-aT.y, ci, nr);
    float ni = fmaf(aT.x, ci, sl.y);
    ni = fmaf(aT.y, cr, ni);
    cr = nr; ci = ni;
  }
}

// ---------------- scan kernel C: full scan w/ carry + output dot + D + GELU ----
__global__ __launch_bounds__(256) void k_scanC(const float* __restrict__ X,
                                               const float* __restrict__ cA,
                                               const float* __restrict__ cC,
                                               const float* __restrict__ S,
                                               const float* __restrict__ Dp,
                                               float* __restrict__ G, int layer) {
  int h = threadIdx.x;
  int c = blockIdx.x;
  int b = blockIdx.y;
  const float2* a2 = (const float2*)(cA + (size_t)((layer * Hn + h) * N2n) * 2);
  const float2* c2 = (const float2*)(cC + (size_t)((layer * Hn + h) * N2n) * 2);
  const float2* s2 = (const float2*)S + ((size_t)(b * NCn + c) * N2n) * Hn + h;
  float ar[N2n], ai[N2n], Cr[N2n], Ci[N2n], sr[N2n], si[N2n];
#pragma unroll
  for (int n = 0; n < N2n; n++) {
    float2 va = a2[n];  ar[n] = va.x; ai[n] = va.y;
    float2 vc = c2[n];  Cr[n] = vc.x; Ci[n] = vc.y;
    float2 vs = s2[(size_t)n * Hn]; sr[n] = vs.x; si[n] = vs.y;
  }
  float Dh = Dp[layer * Hn + h];
  const float* xp = X + (size_t)(b * Ln + c * Tn) * Hn + h;
  float* gp = G + (size_t)(b * Ln + c * Tn) * Hn + h;
  float u = xp[0];
  for (int t = 0; t < Tn; t++) {
    float unext = xp[(t + 1) * Hn];
    float y00 = 0.0f, y01 = 0.0f, y10 = 0.0f, y11 = 0.0f;
#pragma unroll
    for (int n = 0; n < N2n; n++) {
      float tr = fmaf(ar[n], sr[n], u);
      tr = fmaf(-ai[n], si[n], tr);
      float ti = ar[n] * si[n];
      ti = fmaf(ai[n], sr[n], ti);
      sr[n] = tr; si[n] = ti;
      if (n & 1) { y01 = fmaf(Cr[n], tr, y01); y11 = fmaf(Ci[n], ti, y11); }
      else       { y00 = fmaf(Cr[n], tr, y00); y10 = fmaf(Ci[n], ti, y10); }
    }
    float y = (y00 + y01) - (y10 + y11) + Dh * u;
    float g = 0.5f * y * (1.0f + erff(y * 0.70710678118654752f));  // exact erf-GELU
    gp[t * Hn] = g;
    u = unext;
  }
}

// ---------------- GLU: z = Wg @ g + bg ; x = z_a * sigmoid(z_g) ----------------
constexpr int ROWS_GL = 32;
__global__ __launch_bounds__(256) void k_glu(const float* __restrict__ G,
                                             const float* __restrict__ Wgt,
                                             const float* __restrict__ bglu,
                                             float* __restrict__ X, int layer) {
  __shared__ __align__(16) float at[ROWS_GL * Hn];  // 32 KB
  int m0 = blockIdx.x * ROWS_GL;
  int h = threadIdx.x;
  for (int i = h; i < ROWS_GL * Hn; i += 256) at[i] = G[(size_t)m0 * Hn + i];
  __syncthreads();
  const float* wt = Wgt + (size_t)layer * Hn * 2 * Hn;
  float acca[ROWS_GL], accg[ROWS_GL];
#pragma unroll
  for (int r = 0; r < ROWS_GL; r++) { acca[r] = 0.0f; accg[r] = 0.0f; }
  for (int k = 0; k < Hn; k += 4) {
    const float* wk = wt + (size_t)k * 2 * Hn + h;
    float wa0 = wk[0 * Hn], wg0 = wk[1 * Hn];
    float wa1 = wk[2 * Hn], wg1 = wk[3 * Hn];
    float wa2 = wk[4 * Hn], wg2 = wk[5 * Hn];
    float wa3 = wk[6 * Hn], wg3 = wk[7 * Hn];
#pragma unroll
    for (int r = 0; r < ROWS_GL; r++) {
      const float4 av = *(const float4*)&at[r * Hn + k];  // broadcast, conflict-free
      float t0 = acca[r];
      t0 = fmaf(av.x, wa0, t0); t0 = fmaf(av.y, wa1, t0);
      t0 = fmaf(av.z, wa2, t0); t0 = fmaf(av.w, wa3, t0);
      acca[r] = t0;
      float t1 = accg[r];
      t1 = fmaf(av.x, wg0, t1); t1 = fmaf(av.y, wg1, t1);
      t1 = fmaf(av.z, wg2, t1); t1 = fmaf(av.w, wg3, t1);
      accg[r] = t1;
    }
  }
  float ba = bglu[layer * 2 * Hn + h];
  float bg = bglu[layer * 2 * Hn + Hn + h];
#pragma unroll
  for (int r = 0; r < ROWS_GL; r++) {
    float za = acca[r] + ba;
    float zg = accg[r] + bg;
    X[(size_t)(m0 + r) * Hn + h] = za / (1.0f + expf(-zg));
  }
}

// ---------------- output projection: (B*L,256) @ (256,2) + b -------------------
__global__ __launch_bounds__(256) void k_outproj(const float* __restrict__ X,
                                                 const float* __restrict__ Wout,
                                                 const float* __restrict__ b_out,
                                                 float* __restrict__ out) {
  int row = blockIdx.x * 4 + (threadIdx.x >> 6);
  int lane = threadIdx.x & 63;
  const float4 xv = *(const float4*)&X[(size_t)row * Hn + lane * 4];
  const float4 w01 = *(const float4*)&Wout[lane * 8];
  const float4 w23 = *(const float4*)&Wout[lane * 8 + 4];
  float p0 = xv.x * w01.x + xv.y * w01.z + xv.z * w23.x + xv.w * w23.z;
  float p1 = xv.x * w01.y + xv.y * w01.w + xv.z * w23.y + xv.w * w23.w;
  for (int off = 32; off; off >>= 1) {
    p0 += __shfl_down(p0, off, 64);
    p1 += __shfl_down(p1, off, 64);
  }
  if (lane == 0) {
    out[(size_t)row * 2 + 0] = p0 + b_out[0];
    out[(size_t)row * 2 + 1] = p1 + b_out[1];
  }
}

extern "C" void kernel_launch(void* const* d_in, const int* in_sizes, int n_in,
                              void* d_out, int out_size, void* d_ws, size_t ws_size,
                              hipStream_t stream) {
  const float* nin        = (const float*)d_in[0];
  const float* Win        = (const float*)d_in[1];
  const float* b_in       = (const float*)d_in[2];
  const float* C2         = (const float*)d_in[3];
  const float* log_dt     = (const float*)d_in[4];
  const float* log_A_real = (const float*)d_in[5];
  const float* A_imag     = (const float*)d_in[6];
  const float* Dp         = (const float*)d_in[7];
  const float* Wglu       = (const float*)d_in[8];
  const float* bglu       = (const float*)d_in[9];
  const float* Wout       = (const float*)d_in[10];
  const float* b_out      = (const float*)d_in[11];
  float* out = (float*)d_out;

  // workspace layout (floats): X 16.78M | G 16.78M | S 8.39M | cA/cAT/cC 65.5K*3 | Wgt 524K
  float* ws = (float*)d_ws;
  float* X   = ws;
  float* G   = X + (size_t)Bn * Ln * Hn;
  float* S   = G + (size_t)Bn * Ln * Hn;
  float* cA  = S + (size_t)Bn * NCn * Hn * N2n * 2;
  float* cAT = cA + (size_t)NLn * Hn * N2n * 2;
  float* cC  = cAT + (size_t)NLn * Hn * N2n * 2;
  float* Wgt = cC + (size_t)NLn * Hn * N2n * 2;

  k_consts<<<(NLn * Hn * N2n + 255) / 256, 256, 0, stream>>>(C2, log_dt, log_A_real, A_imag, cA, cAT, cC);
  k_wgt<<<(NLn * 2 * Hn * Hn + 255) / 256, 256, 0, stream>>>(Wglu, Wgt);
  k_inproj<<<Bn * Ln / ROWS_IP, 256, 0, stream>>>(nin, Win, b_in, X);
  for (int l = 0; l < NLn; l++) {
    k_scanA<<<dim3(NCn, Bn), 256, 0, stream>>>(X, cA, S, l);
    k_scanB<<<(Bn * Hn * N2n + 255) / 256, 256, 0, stream>>>(S, cAT, l);
    k_scanC<<<dim3(NCn, Bn), 256, 0, stream>>>(X, cA, cC, S, Dp, G, l);
    k_glu<<<Bn * Ln / ROWS_GL, 256, 0, stream>>>(G, Wgt, bglu, X, l);
  }
  k_outproj<<<Bn * Ln / 4, 256, 0, stream>>>(X, Wout, b_out, out);
}

// Round 2
// 1543.393 us; speedup vs baseline: 1.5809x; 1.5809x over previous
//
#include <hip/hip_runtime.h>
#include <math.h>

typedef unsigned short ushort_t;
typedef __attribute__((ext_vector_type(8))) short short8;
typedef __attribute__((ext_vector_type(8))) unsigned short ushort8;
typedef __attribute__((ext_vector_type(4))) float f32x4;

constexpr int Bn = 32, Ln = 2048, IN_DIM = 182, OUT_DIM = 2;
constexpr int Hn = 256, N2n = 32, NLn = 4;
constexpr int Tn = 64, NCn = Ln / Tn;   // 32 chunks of 64 steps
constexpr int KGn = Hn / 8;             // 32 k-groups of 8
constexpr int RG_BYTES = KGn * 256;     // 8192 B per 16-row group (full K)

__device__ inline ushort_t f2bf(float f) {
  unsigned int u = __float_as_uint(f);
  u += 0x7fffu + ((u >> 16) & 1u);      // RNE
  return (ushort_t)(u >> 16);
}

// ---------------- per-layer constants: a = exp(dt*A), a^Tn, C' = 2*C*(a-1)/A ---
__global__ void k_consts(const float* __restrict__ C2, const float* __restrict__ log_dt,
                         const float* __restrict__ log_A_real, const float* __restrict__ A_imag,
                         float* __restrict__ cA, float* __restrict__ cAT, float* __restrict__ cC) {
  int idx = blockIdx.x * blockDim.x + threadIdx.x;  // l*H*N2 + h*N2 + n
  if (idx >= NLn * Hn * N2n) return;
  int lh = idx / N2n;
  int h = lh % Hn;
  int l = lh / Hn;
  float dt = expf(log_dt[l * Hn + h]);
  float Ar = -expf(log_A_real[idx]);
  float Ai = A_imag[idx];
  float dr = Ar * dt, di = Ai * dt;
  float ea = expf(dr);
  float ar = ea * cosf(di), ai = ea * sinf(di);
  float eT = expf(dr * (float)Tn);
  float aTr = eT * cosf(di * (float)Tn), aTi = eT * sinf(di * (float)Tn);
  float nr = ar - 1.0f, ni = ai;
  float inv = 1.0f / (Ar * Ar + Ai * Ai);
  float qr = (nr * Ar + ni * Ai) * inv;
  float qi = (ni * Ar - nr * Ai) * inv;
  float c2r = C2[idx * 2 + 0], c2i = C2[idx * 2 + 1];
  cA[idx * 2 + 0] = ar;   cA[idx * 2 + 1] = ai;
  cAT[idx * 2 + 0] = aTr; cAT[idx * 2 + 1] = aTi;
  cC[idx * 2 + 0] = 2.0f * (c2r * qr - c2i * qi);
  cC[idx * 2 + 1] = 2.0f * (c2r * qi + c2i * qr);
}

// ---------------- Wglu (l,o,k) fp32 -> Wf bf16 frag layout [l][o/16][k/8][16][8]
__global__ void k_wf(const float* __restrict__ Wglu, ushort_t* __restrict__ Wf) {
  int idx = blockIdx.x * blockDim.x + threadIdx.x;  // l*512*256 + o*256 + k
  if (idx >= NLn * 2 * Hn * Hn) return;
  int k = idx & 255;
  int o = (idx >> 8) & 511;
  int l = idx >> 17;
  size_t off = (size_t)l * (32 * RG_BYTES) + (size_t)(o >> 4) * RG_BYTES
             + (size_t)(k >> 3) * 256 + (o & 15) * 16 + (k & 7) * 2;
  *(ushort_t*)((char*)Wf + off) = f2bf(Wglu[idx]);
}

// ---------------- input projection: (B*L,182) @ (182,256) + b -> X (B,L,H) -----
constexpr int ROWS_IP = 32;
__global__ __launch_bounds__(256) void k_inproj(const float* __restrict__ nin,
                                                const float* __restrict__ Win,
                                                const float* __restrict__ b_in,
                                                float* __restrict__ X) {
  __shared__ __align__(16) float at[ROWS_IP * IN_DIM];
  int m0 = blockIdx.x * ROWS_IP;
  int h = threadIdx.x;
  for (int i = h; i < ROWS_IP * IN_DIM; i += 256) at[i] = nin[(size_t)m0 * IN_DIM + i];
  __syncthreads();
  float acc[ROWS_IP];
#pragma unroll
  for (int r = 0; r < ROWS_IP; r++) acc[r] = 0.0f;
  for (int k = 0; k < IN_DIM; k += 2) {
    float w0 = Win[k * Hn + h];
    float w1 = Win[(k + 1) * Hn + h];
#pragma unroll
    for (int r = 0; r < ROWS_IP; r++) {
      acc[r] = fmaf(at[r * IN_DIM + k], w0, acc[r]);
      acc[r] = fmaf(at[r * IN_DIM + k + 1], w1, acc[r]);
    }
  }
  float bb = b_in[h];
#pragma unroll
  for (int r = 0; r < ROWS_IP; r++) X[(size_t)(m0 + r) * Hn + h] = acc[r] + bb;
}

// ---------------- scan kernel A: per-chunk local end-state (zero init) ---------
__global__ __launch_bounds__(256) void k_scanA(const float* __restrict__ X,
                                               const float* __restrict__ cA,
                                               float* __restrict__ S, int layer) {
  __shared__ __align__(16) float xt[Tn * 256];  // 64 KB, XOR-swizzled rows
  int h = threadIdx.x;
  int c = blockIdx.x;
  int b = blockIdx.y;
  const float4* xs = (const float4*)(X + (size_t)(b * Ln + c * Tn) * Hn);
#pragma unroll
  for (int i = 0; i < 16; i++) {
    int e = i * 256 + h;
    int t = e >> 6;
    int pos = ((e & 63) * 4) ^ ((t & 7) << 2);
    *(float4*)&xt[t * 256 + pos] = xs[e];
  }
  __syncthreads();
  const float2* a2 = (const float2*)(cA + (size_t)((layer * Hn + h) * N2n) * 2);
  float ar[N2n], ai[N2n], sr[N2n], si[N2n];
#pragma unroll
  for (int n = 0; n < N2n; n++) {
    float2 v = a2[n];
    ar[n] = v.x; ai[n] = v.y; sr[n] = 0.0f; si[n] = 0.0f;
  }
  for (int t = 0; t < Tn; t++) {
    float u = xt[t * 256 + (h ^ ((t & 7) << 2))];
#pragma unroll
    for (int n = 0; n < N2n; n++) {
      float tr = fmaf(ar[n], sr[n], u);
      tr = fmaf(-ai[n], si[n], tr);
      float ti = ar[n] * si[n];
      ti = fmaf(ai[n], sr[n], ti);
      sr[n] = tr; si[n] = ti;
    }
  }
  float2* sp = (float2*)S + ((size_t)(b * NCn + c) * N2n) * Hn + h;
#pragma unroll
  for (int n = 0; n < N2n; n++) sp[(size_t)n * Hn] = make_float2(sr[n], si[n]);
}

// ---------------- scan kernel B: carry scan across chunks (in place) -----------
__global__ void k_scanB(float* __restrict__ S, const float* __restrict__ cAT, int layer) {
  int idx = blockIdx.x * blockDim.x + threadIdx.x;  // b*(N2*H) + n*H + h
  if (idx >= Bn * Hn * N2n) return;
  int h = idx % Hn;
  int n = (idx / Hn) % N2n;
  int b = idx / (Hn * N2n);
  const float2 aT = *(const float2*)(cAT + (size_t)((layer * Hn + h) * N2n + n) * 2);
  float cr = 0.0f, ci = 0.0f;
  for (int c = 0; c < NCn; c++) {
    float2* sp = (float2*)S + ((size_t)(b * NCn + c) * N2n + n) * Hn + h;
    float2 sl = *sp;
    *sp = make_float2(cr, ci);
    float nr = fmaf(aT.x, cr, sl.x);
    nr = fmaf(-aT.y, ci, nr);
    float ni = fmaf(aT.x, ci, sl.y);
    ni = fmaf(aT.y, cr, ni);
    cr = nr; ci = ni;
  }
}

// ---------------- scan kernel C: scan w/ carry + dot + D + GELU -> G bf16 frags
__global__ __launch_bounds__(256) void k_scanC(const float* __restrict__ X,
                                               const float* __restrict__ cA,
                                               const float* __restrict__ cC,
                                               const float* __restrict__ S,
                                               const float* __restrict__ Dp,
                                               ushort_t* __restrict__ Gf, int layer) {
  __shared__ __align__(16) float xt[Tn * 256];  // 64 KB, XOR-swizzled rows
  int h = threadIdx.x;
  int c = blockIdx.x;
  int b = blockIdx.y;
  const float4* xs = (const float4*)(X + (size_t)(b * Ln + c * Tn) * Hn);
#pragma unroll
  for (int i = 0; i < 16; i++) {
    int e = i * 256 + h;
    int t = e >> 6;
    int pos = ((e & 63) * 4) ^ ((t & 7) << 2);
    *(float4*)&xt[t * 256 + pos] = xs[e];
  }
  __syncthreads();
  const float2* a2 = (const float2*)(cA + (size_t)((layer * Hn + h) * N2n) * 2);
  const float2* c2 = (const float2*)(cC + (size_t)((layer * Hn + h) * N2n) * 2);
  const float2* s2 = (const float2*)S + ((size_t)(b * NCn + c) * N2n) * Hn + h;
  float ar[N2n], ai[N2n], Cr[N2n], Ci[N2n], sr[N2n], si[N2n];
#pragma unroll
  for (int n = 0; n < N2n; n++) {
    float2 va = a2[n];  ar[n] = va.x; ai[n] = va.y;
    float2 vc = c2[n];  Cr[n] = vc.x; Ci[n] = vc.y;
    float2 vs = s2[(size_t)n * Hn]; sr[n] = vs.x; si[n] = vs.y;
  }
  float Dh = Dp[layer * Hn + h];
  for (int t = 0; t < Tn; t++) {
    int slot = t * 256 + (h ^ ((t & 7) << 2));
    float u = xt[slot];
    float y00 = 0.0f, y01 = 0.0f, y10 = 0.0f, y11 = 0.0f;
#pragma unroll
    for (int n = 0; n < N2n; n++) {
      float tr = fmaf(ar[n], sr[n], u);
      tr = fmaf(-ai[n], si[n], tr);
      float ti = ar[n] * si[n];
      ti = fmaf(ai[n], sr[n], ti);
      sr[n] = tr; si[n] = ti;
      if (n & 1) { y01 = fmaf(Cr[n], tr, y01); y11 = fmaf(Ci[n], ti, y11); }
      else       { y00 = fmaf(Cr[n], tr, y00); y10 = fmaf(Ci[n], ti, y10); }
    }
    float y = (y00 + y01) - (y10 + y11) + Dh * u;
    xt[slot] = 0.5f * y * (1.0f + erff(y * 0.70710678118654752f));  // in-place g
  }
  __syncthreads();
  // bulk write: chunk = 4 contiguous rowgroups = 32 KB of G frag layout
  char* gb = (char*)Gf + (size_t)(b * 128 + c * 4) * RG_BYTES;
#pragma unroll
  for (int it = 0; it < 8; it++) {
    int p = it * 4096 + h * 16;            // byte offset in region
    int R = p >> 13;
    int kg = (p >> 8) & 31;
    int row = (p >> 4) & 15;
    int t = R * 16 + row;
    int h0 = kg * 8;
    int sw = (t & 7) << 2;
    const float* rp = &xt[t * 256];
    float4 f0 = *(const float4*)&rp[h0 ^ sw];
    float4 f1 = *(const float4*)&rp[(h0 + 4) ^ sw];
    ushort8 o;
    o[0] = f2bf(f0.x); o[1] = f2bf(f0.y); o[2] = f2bf(f0.z); o[3] = f2bf(f0.w);
    o[4] = f2bf(f1.x); o[5] = f2bf(f1.y); o[6] = f2bf(f1.z); o[7] = f2bf(f1.w);
    *(ushort8*)(gb + p) = o;
  }
}

// ---------------- GLU via MFMA: z = G @ W^T + b ; X = z_a * sigmoid(z_g) -------
// G frag layout [M/16][K/8][16][8] bf16; Wf [o/16][k/8][16][8] bf16 per layer.
// Block: 4 waves (2x2), tile 128 rows x (64 a-cols + 64 g-cols). No K-loop barriers.
__global__ __launch_bounds__(256) void k_glu(const ushort_t* __restrict__ Gf,
                                             const ushort_t* __restrict__ Wf,
                                             const float* __restrict__ bglu,
                                             float* __restrict__ X, int layer) {
  __shared__ __align__(16) ushort_t wlds[8 * 4096];  // 8 o-tiles x 8 KB = 64 KB
  int tid = threadIdx.x;
  int bx = blockIdx.x;   // 512 M-blocks
  int nb = blockIdx.y;   // 4 N-blocks
  int lane = tid & 63;
  int wave = tid >> 6;
  int wm = wave >> 1, wn = wave & 1;
  const char* wbase = (const char*)Wf + (size_t)layer * 32 * RG_BYTES;
#pragma unroll
  for (int i = 0; i < 16; i++) {
    int tt = i >> 1, hh = i & 1;
    int ot = (tt < 4) ? (nb * 4 + tt) : (16 + nb * 4 + (tt - 4));
    ((float4*)wlds)[i * 256 + tid] =
        *(const float4*)(wbase + (size_t)ot * RG_BYTES + hh * 4096 + tid * 16);
  }
  __syncthreads();

  const char* gb = (const char*)Gf + (size_t)(bx * 8 + wm * 4) * RG_BYTES + lane * 16;
  const char* lb = (const char*)wlds + (size_t)(wn * 2) * RG_BYTES + lane * 16;
  f32x4 acc[4][4] = {};
#pragma unroll 2
  for (int ks = 0; ks < 8; ks++) {
    short8 a[4], bf[4];
#pragma unroll
    for (int rg = 0; rg < 4; rg++) a[rg] = *(const short8*)(gb + rg * RG_BYTES + ks * 1024);
#pragma unroll
    for (int ct = 0; ct < 2; ct++) {
      bf[ct]     = *(const short8*)(lb + ct * RG_BYTES + ks * 1024);
      bf[ct + 2] = *(const short8*)(lb + (4 + ct) * RG_BYTES + ks * 1024);
    }
#pragma unroll
    for (int rg = 0; rg < 4; rg++)
#pragma unroll
      for (int ct = 0; ct < 4; ct++)
        acc[rg][ct] = __builtin_amdgcn_mfma_f32_16x16x32_bf16(a[rg], bf[ct], acc[rg][ct], 0, 0, 0);
  }

  int c0 = nb * 64 + wn * 32;
  int mw = bx * 128 + wm * 64;
#pragma unroll
  for (int rg = 0; rg < 4; rg++) {
#pragma unroll
    for (int ct = 0; ct < 2; ct++) {
      int j = c0 + ct * 16 + (lane & 15);
      float ba = bglu[layer * 512 + j];
      float bg = bglu[layer * 512 + 256 + j];
      f32x4 va = acc[rg][ct], vg = acc[rg][ct + 2];
      int r0 = mw + rg * 16 + (lane >> 4) * 4;
#pragma unroll
      for (int r = 0; r < 4; r++) {
        float za = va[r] + ba;
        float zg = vg[r] + bg;
        X[(size_t)(r0 + r) * Hn + j] = za / (1.0f + expf(-zg));
      }
    }
  }
}

// ---------------- output projection: (B*L,256) @ (256,2) + b -------------------
__global__ __launch_bounds__(256) void k_outproj(const float* __restrict__ X,
                                                 const float* __restrict__ Wout,
                                                 const float* __restrict__ b_out,
                                                 float* __restrict__ out) {
  int row = blockIdx.x * 4 + (threadIdx.x >> 6);
  int lane = threadIdx.x & 63;
  const float4 xv = *(const float4*)&X[(size_t)row * Hn + lane * 4];
  const float4 w01 = *(const float4*)&Wout[lane * 8];
  const float4 w23 = *(const float4*)&Wout[lane * 8 + 4];
  float p0 = xv.x * w01.x + xv.y * w01.z + xv.z * w23.x + xv.w * w23.z;
  float p1 = xv.x * w01.y + xv.y * w01.w + xv.z * w23.y + xv.w * w23.w;
  for (int off = 32; off; off >>= 1) {
    p0 += __shfl_down(p0, off, 64);
    p1 += __shfl_down(p1, off, 64);
  }
  if (lane == 0) {
    out[(size_t)row * 2 + 0] = p0 + b_out[0];
    out[(size_t)row * 2 + 1] = p1 + b_out[1];
  }
}

extern "C" void kernel_launch(void* const* d_in, const int* in_sizes, int n_in,
                              void* d_out, int out_size, void* d_ws, size_t ws_size,
                              hipStream_t stream) {
  const float* nin        = (const float*)d_in[0];
  const float* Win        = (const float*)d_in[1];
  const float* b_in       = (const float*)d_in[2];
  const float* C2         = (const float*)d_in[3];
  const float* log_dt     = (const float*)d_in[4];
  const float* log_A_real = (const float*)d_in[5];
  const float* A_imag     = (const float*)d_in[6];
  const float* Dp         = (const float*)d_in[7];
  const float* Wglu       = (const float*)d_in[8];
  const float* bglu       = (const float*)d_in[9];
  const float* Wout       = (const float*)d_in[10];
  const float* b_out      = (const float*)d_in[11];
  float* out = (float*)d_out;

  // ws floats: X 16.78M | S 16.78M | cA/cAT/cC 65.5K*3 | Wf 0.5M bf16 | Gf 16.78M bf16
  float* ws = (float*)d_ws;
  float* X   = ws;
  float* S   = X + (size_t)Bn * Ln * Hn;
  float* cA  = S + (size_t)Bn * NCn * Hn * N2n * 2;
  float* cAT = cA + (size_t)NLn * Hn * N2n * 2;
  float* cC  = cAT + (size_t)NLn * Hn * N2n * 2;
  ushort_t* Wf = (ushort_t*)(cC + (size_t)NLn * Hn * N2n * 2);
  ushort_t* Gf = Wf + (size_t)NLn * 2 * Hn * Hn;

  k_consts<<<(NLn * Hn * N2n + 255) / 256, 256, 0, stream>>>(C2, log_dt, log_A_real, A_imag, cA, cAT, cC);
  k_wf<<<(NLn * 2 * Hn * Hn + 255) / 256, 256, 0, stream>>>(Wglu, Wf);
  k_inproj<<<Bn * Ln / ROWS_IP, 256, 0, stream>>>(nin, Win, b_in, X);
  for (int l = 0; l < NLn; l++) {
    k_scanA<<<dim3(NCn, Bn), 256, 0, stream>>>(X, cA, S, l);
    k_scanB<<<(Bn * Hn * N2n + 255) / 256, 256, 0, stream>>>(S, cAT, l);
    k_scanC<<<dim3(NCn, Bn), 256, 0, stream>>>(X, cA, cC, S, Dp, Gf, l);
    k_glu<<<dim3(Bn * Ln / 128, 4), 256, 0, stream>>>(Gf, Wf, bglu, X, l);
  }
  k_outproj<<<Bn * Ln / 4, 256, 0, stream>>>(X, Wout, b_out, out);
}

// Round 3
// 586.024 us; speedup vs baseline: 4.1637x; 2.6337x over previous
//
#include <hip/hip_runtime.h>
#include <math.h>

typedef unsigned short u16;
typedef __attribute__((ext_vector_type(2))) unsigned short ushort2_t;
typedef __attribute__((ext_vector_type(4))) unsigned short ushort4_t;
typedef __attribute__((ext_vector_type(8))) unsigned short ushort8_t;
typedef __attribute__((ext_vector_type(8))) short short8;
typedef __attribute__((ext_vector_type(4))) float f32x4;

constexpr int Bn = 32, Ln = 2048, IN_DIM = 182, OUT_DIM = 2;
constexpr int Hn = 256, N2n = 32, NLn = 4;
constexpr int Tn = 64, NCn = Ln / Tn;      // 32 chunks of 64 steps
constexpr int KP = 192;                    // padded K for input proj

__device__ inline u16 f2bf(float f) {
  unsigned int u = __float_as_uint(f);
  u += 0x7fffu + ((u >> 16) & 1u);         // RNE
  return (u16)(u >> 16);
}
__device__ inline float bf2f(u16 v) { return __uint_as_float(((unsigned int)v) << 16); }

// ---- per-layer scalar constants: aT = a^64, C' = 2C(a-1)/A, (dr,di) = dt*A ----
__global__ void k_consts(const float* __restrict__ C2, const float* __restrict__ log_dt,
                         const float* __restrict__ log_A_real, const float* __restrict__ A_imag,
                         float* __restrict__ cAT, float* __restrict__ cC, float* __restrict__ cDt) {
  int idx = blockIdx.x * blockDim.x + threadIdx.x;  // l*H*N2 + h*N2 + n
  if (idx >= NLn * Hn * N2n) return;
  int lh = idx / N2n;
  int h = lh % Hn;
  int l = lh / Hn;
  float dt = expf(log_dt[l * Hn + h]);
  float Ar = -expf(log_A_real[idx]);
  float Ai = A_imag[idx];
  float dr = Ar * dt, di = Ai * dt;
  float ea = expf(dr);
  float ar = ea * cosf(di), ai = ea * sinf(di);
  float eT = expf(dr * (float)Tn);
  cAT[idx * 2 + 0] = eT * cosf(di * (float)Tn);
  cAT[idx * 2 + 1] = eT * sinf(di * (float)Tn);
  float nr = ar - 1.0f, ni = ai;
  float inv = 1.0f / (Ar * Ar + Ai * Ai);
  float qr = (nr * Ar + ni * Ai) * inv;
  float qi = (ni * Ar - nr * Ai) * inv;
  float c2r = C2[idx * 2 + 0], c2i = C2[idx * 2 + 1];
  cC[idx * 2 + 0] = 2.0f * (c2r * qr - c2i * qi);
  cC[idx * 2 + 1] = 2.0f * (c2r * qi + c2i * qr);
  cDt[idx * 2 + 0] = dr;
  cDt[idx * 2 + 1] = di;
}

// ---- k_h[delta] table: k[d] = sum_n Re(C'_n a_n^d) ------------------------------
__global__ void k_ktab(const float* __restrict__ cDt, const float* __restrict__ cC,
                       float* __restrict__ ktab) {
  int idx = blockIdx.x * blockDim.x + threadIdx.x;  // (l*H + h)*64 + d
  if (idx >= NLn * Hn * Tn) return;
  int d = idx & 63;
  int lh = idx >> 6;
  float fd = (float)d;
  float acc = 0.0f;
  for (int n = 0; n < N2n; n++) {
    float dr = cDt[(lh * N2n + n) * 2 + 0], di = cDt[(lh * N2n + n) * 2 + 1];
    float Cr = cC[(lh * N2n + n) * 2 + 0], Ci = cC[(lh * N2n + n) * 2 + 1];
    float ex = expf(dr * fd);
    acc += ex * (Cr * cosf(di * fd) - Ci * sinf(di * fd));
  }
  ktab[idx] = acc;
}

// ---- build Lm/Em/Fm 64x64 bf16 matrices per (layer, h) --------------------------
// Lm[t][tau] = (t>=tau) ? k[t-tau] + (t==tau)*D : 0
// Em[2n][tau] = Re(a^(63-tau)), Em[2n+1][tau] = Im(a^(63-tau))
// Fm[t][2n] = Re(C' a^(t+1)),  Fm[t][2n+1] = -Im(C' a^(t+1))
__global__ void k_build(const float* __restrict__ cDt, const float* __restrict__ cC,
                        const float* __restrict__ ktab, const float* __restrict__ Dp,
                        u16* __restrict__ Lm, u16* __restrict__ Em, u16* __restrict__ Fm) {
  int h = blockIdx.x;
  int ym = blockIdx.y;         // l*3 + mat
  int l = ym / 3, mat = ym % 3;
  int tid = threadIdx.x;
  int row = tid >> 2, tq = (tid & 3) * 16;
  int lh = l * Hn + h;
  u16 vals[16];
  if (mat == 0) {
    float Dh = Dp[lh];
    for (int j = 0; j < 16; j++) {
      int tau = tq + j;
      int d = row - tau;
      float v = 0.0f;
      if (d >= 0) { v = ktab[lh * 64 + d]; if (d == 0) v += Dh; }
      vals[j] = f2bf(v);
    }
  } else if (mat == 1) {
    int n = row >> 1, im = row & 1;
    float dr = cDt[(lh * N2n + n) * 2 + 0], di = cDt[(lh * N2n + n) * 2 + 1];
    for (int j = 0; j < 16; j++) {
      float p = (float)(63 - (tq + j));
      float ex = expf(dr * p);
      vals[j] = f2bf(im ? ex * sinf(di * p) : ex * cosf(di * p));
    }
  } else {
    float p = (float)(row + 1);
    for (int j = 0; j < 16; j++) {
      int comp = tq + j;
      int n = comp >> 1, im = comp & 1;
      float dr = cDt[(lh * N2n + n) * 2 + 0], di = cDt[(lh * N2n + n) * 2 + 1];
      float Cr = cC[(lh * N2n + n) * 2 + 0], Ci = cC[(lh * N2n + n) * 2 + 1];
      float ex = expf(dr * p), co = cosf(di * p), si = sinf(di * p);
      vals[j] = f2bf(im ? -(ex * (Cr * si + Ci * co)) : ex * (Cr * co - Ci * si));
    }
  }
  u16* dst = (mat == 0 ? Lm : mat == 1 ? Em : Fm) + (size_t)lh * 4096 + row * 64 + tq;
  ushort8_t o0, o1;
  for (int j = 0; j < 8; j++) { o0[j] = vals[j]; o1[j] = vals[8 + j]; }
  *(ushort8_t*)dst = o0;
  *(ushort8_t*)(dst + 8) = o1;
}

// ---- Wglu (l,o,k) fp32 -> Wf bf16 frag layout [l][o/16][k/8][16][8] (verified) --
__global__ void k_wf(const float* __restrict__ Wglu, u16* __restrict__ Wf) {
  int idx = blockIdx.x * blockDim.x + threadIdx.x;  // l*512*256 + o*256 + k
  if (idx >= NLn * 2 * Hn * Hn) return;
  int k = idx & 255;
  int o = (idx >> 8) & 511;
  int l = idx >> 17;
  size_t off = (size_t)l * (32 * 8192) + (size_t)(o >> 4) * 8192
             + (size_t)(k >> 3) * 256 + (o & 15) * 16 + (k & 7) * 2;
  *(u16*)((char*)Wf + off) = f2bf(Wglu[idx]);
}

// ---- nin fp32 (m,182) -> Af bf16 [m][192] (zero pad) ----------------------------
__global__ void k_cvt(const float* __restrict__ nin, u16* __restrict__ Af) {
  int idx = blockIdx.x * blockDim.x + threadIdx.x;
  if (idx >= Bn * Ln * KP) return;
  int m = idx / KP, k = idx - m * KP;
  Af[idx] = (k < IN_DIM) ? f2bf(nin[(size_t)m * IN_DIM + k]) : (u16)0;
}

// ---- Win fp32 (182,256) -> Wt bf16 [h][192] -------------------------------------
__global__ void k_wtin(const float* __restrict__ Win, u16* __restrict__ Wt) {
  int idx = blockIdx.x * blockDim.x + threadIdx.x;
  if (idx >= Hn * KP) return;
  int h = idx / KP, k = idx - h * KP;
  Wt[idx] = (k < IN_DIM) ? f2bf(Win[(size_t)k * Hn + h]) : (u16)0;
}

// ---- input projection via MFMA -> X_c[b][c][h][t] bf16 --------------------------
__global__ __launch_bounds__(256) void k_inproj(const u16* __restrict__ Af,
                                                const u16* __restrict__ Wt,
                                                const float* __restrict__ b_in,
                                                u16* __restrict__ Xc) {
  int tid = threadIdx.x;
  int nb = blockIdx.x;   // 2
  int bx = blockIdx.y;   // 512
  int lane = tid & 63, wave = tid >> 6;
  int wm = wave >> 1, wn = wave & 1;
  int l15 = lane & 15, l4 = lane >> 4;
  int m0 = bx * 128 + wm * 64;
  int h0 = nb * 128 + wn * 64;
  f32x4 acc[4][4] = {};
#pragma unroll 2
  for (int ks = 0; ks < 6; ks++) {
    short8 a[4], bfr[4];
#pragma unroll
    for (int mt = 0; mt < 4; mt++)
      a[mt] = *(const short8*)(Af + (size_t)(m0 + mt * 16 + l15) * KP + ks * 32 + l4 * 8);
#pragma unroll
    for (int nt = 0; nt < 4; nt++)
      bfr[nt] = *(const short8*)(Wt + (size_t)(h0 + nt * 16 + l15) * KP + ks * 32 + l4 * 8);
#pragma unroll
    for (int mt = 0; mt < 4; mt++)
#pragma unroll
      for (int nt = 0; nt < 4; nt++)
        acc[mt][nt] = __builtin_amdgcn_mfma_f32_16x16x32_bf16(a[mt], bfr[nt], acc[mt][nt], 0, 0, 0);
  }
#pragma unroll
  for (int mt = 0; mt < 4; mt++) {
#pragma unroll
    for (int nt = 0; nt < 4; nt++) {
      int j = h0 + nt * 16 + l15;
      float bb = b_in[j];
      int r0 = m0 + mt * 16 + l4 * 4;
      int b = r0 >> 11, li = r0 & 2047;
      int c = li >> 6, t0 = li & 63;
      ushort4_t w;
#pragma unroll
      for (int r = 0; r < 4; r++) w[r] = f2bf(acc[mt][nt][r] + bb);
      *(ushort4_t*)(Xc + ((size_t)(b * NCn + c) * Hn + j) * Tn + t0) = w;
    }
  }
}

// ---- fused S4D layer: E@U -> carry scan -> L@U + F@carry -> GELU -> Gf planes ---
// Xc[b][c][h][t] bf16 in; Gf[h/8][b][l][8] bf16 out.
__global__ __launch_bounds__(256) void k_s4d(const u16* __restrict__ Xc,
                                             const u16* __restrict__ Lm,
                                             const u16* __restrict__ Em,
                                             const u16* __restrict__ Fm,
                                             const float* __restrict__ cAT,
                                             u16* __restrict__ Gf, int layer) {
  __shared__ __align__(16) char sbuf[32768];  // s_end/carry: [hl(8)][c(32)][64 comp bf16], 16B-grp XOR (c&7)
  __shared__ __align__(16) char ybuf[32768];  // y: [c(32)][hl(8)][16 grp of 8B], grp = (t>>2)^(c&15)
  int tid = threadIdx.x;
  int lane = tid & 63, wave = tid >> 6;
  int l15 = lane & 15, l4 = lane >> 4;
  int b = blockIdx.x;    // 32
  int hg = blockIdx.y;   // 32

  short8 ufr[2][2][2];   // [hi][nt][ks]
  // phase A: load u-frags, E@U -> s_end LDS
  for (int hi = 0; hi < 2; hi++) {
    int hl = wave * 2 + hi;
    int h = hg * 8 + hl;
    const u16* xb = Xc + ((size_t)(b * NCn) * Hn + h) * Tn;
#pragma unroll
    for (int nt = 0; nt < 2; nt++)
#pragma unroll
      for (int ks = 0; ks < 2; ks++)
        ufr[hi][nt][ks] = *(const short8*)(xb + (size_t)(nt * 16 + l15) * (Hn * Tn) + ks * 32 + l4 * 8);
    const u16* eb = Em + (size_t)(layer * Hn + h) * 4096;
#pragma unroll
    for (int mt = 0; mt < 4; mt++) {
      f32x4 sacc[2] = {};
#pragma unroll
      for (int ks = 0; ks < 2; ks++) {
        short8 af = *(const short8*)(eb + (mt * 16 + l15) * 64 + ks * 32 + l4 * 8);
#pragma unroll
        for (int nt = 0; nt < 2; nt++)
          sacc[nt] = __builtin_amdgcn_mfma_f32_16x16x32_bf16(af, ufr[hi][nt][ks], sacc[nt], 0, 0, 0);
      }
      int comp0 = mt * 16 + l4 * 4;
      int g = comp0 >> 3, half = (comp0 >> 2) & 1;
#pragma unroll
      for (int nt = 0; nt < 2; nt++) {
        int c = nt * 16 + l15;
        ushort4_t w;
#pragma unroll
        for (int r = 0; r < 4; r++) w[r] = f2bf(sacc[nt][r]);
        *(ushort4_t*)(sbuf + hl * 4096 + c * 128 + (g ^ (c & 7)) * 16 + half * 8) = w;
      }
    }
  }
  __syncthreads();
  // phase B: carry scan (thread owns (hl, n)); write carry-IN per chunk in place
  {
    int hl = tid >> 5, n = tid & 31;
    int h = hg * 8 + hl;
    float aTr = cAT[((size_t)(layer * Hn + h) * N2n + n) * 2 + 0];
    float aTi = cAT[((size_t)(layer * Hn + h) * N2n + n) * 2 + 1];
    float cr = 0.0f, ci = 0.0f;
    int grp = n >> 2, off = (n & 3) * 4;
    for (int c = 0; c < NCn; c++) {
      char* p = sbuf + hl * 4096 + c * 128 + (grp ^ (c & 7)) * 16 + off;
      ushort2_t sv = *(ushort2_t*)p;
      float sre = bf2f(sv[0]), sim = bf2f(sv[1]);
      ushort2_t cw; cw[0] = f2bf(cr); cw[1] = f2bf(ci);
      *(ushort2_t*)p = cw;
      float nr = aTr * cr - aTi * ci + sre;
      float ni = aTr * ci + aTi * cr + sim;
      cr = nr; ci = ni;
    }
  }
  __syncthreads();
  // phase C: y = L@U + F@carry; GELU; -> ybuf
  for (int hi = 0; hi < 2; hi++) {
    int hl = wave * 2 + hi;
    int h = hg * 8 + hl;
    const u16* lb = Lm + (size_t)(layer * Hn + h) * 4096;
    const u16* fb = Fm + (size_t)(layer * Hn + h) * 4096;
#pragma unroll
    for (int mt = 0; mt < 4; mt++) {
      f32x4 yacc[2] = {};
#pragma unroll
      for (int ks = 0; ks < 2; ks++) {
        short8 af = *(const short8*)(lb + (mt * 16 + l15) * 64 + ks * 32 + l4 * 8);
#pragma unroll
        for (int nt = 0; nt < 2; nt++)
          yacc[nt] = __builtin_amdgcn_mfma_f32_16x16x32_bf16(af, ufr[hi][nt][ks], yacc[nt], 0, 0, 0);
      }
#pragma unroll
      for (int ks = 0; ks < 2; ks++) {
        short8 af = *(const short8*)(fb + (mt * 16 + l15) * 64 + ks * 32 + l4 * 8);
#pragma unroll
        for (int nt = 0; nt < 2; nt++) {
          int c = nt * 16 + l15;
          short8 bf = *(const short8*)(sbuf + hl * 4096 + c * 128 + ((ks * 4 + l4) ^ (c & 7)) * 16);
          yacc[nt] = __builtin_amdgcn_mfma_f32_16x16x32_bf16(af, bf, yacc[nt], 0, 0, 0);
        }
      }
      int t0 = mt * 16 + l4 * 4;
#pragma unroll
      for (int nt = 0; nt < 2; nt++) {
        int c = nt * 16 + l15;
        ushort4_t w;
#pragma unroll
        for (int r = 0; r < 4; r++) {
          float y = yacc[nt][r];
          w[r] = f2bf(0.5f * y * (1.0f + erff(y * 0.70710678118654752f)));
        }
        int g = ((t0 >> 2) ^ (c & 15)) & 15;
        *(ushort4_t*)(ybuf + (c * 8 + hl) * 128 + g * 8) = w;
      }
    }
  }
  __syncthreads();
  // phase D: write Gf plane [hg][b][l][8]
  u16* gp = Gf + (size_t)(hg * Bn + b) * Ln * 8;
  for (int it = 0; it < 8; it++) {
    int m = it * 256 + tid;
    int c = m >> 6, t = m & 63;
    int g = ((t >> 2) ^ (c & 15)) & 15;
    const char* base = ybuf + (c * 8) * 128 + g * 8 + (t & 3) * 2;
    ushort8_t o;
#pragma unroll
    for (int hl = 0; hl < 8; hl++) o[hl] = *(const u16*)(base + hl * 128);
    *(ushort8_t*)(gp + (size_t)m * 8) = o;
  }
}

// ---- GLU via MFMA: A from Gf planes, B from Wf frags; out X_c (or plain last) ---
template <int LAST>
__global__ __launch_bounds__(256) void k_glu(const u16* __restrict__ Gf,
                                             const u16* __restrict__ Wf,
                                             const float* __restrict__ bglu,
                                             u16* __restrict__ Xout, int layer) {
  __shared__ __align__(16) u16 wlds[8 * 4096];
  int tid = threadIdx.x;
  int nb = blockIdx.x;   // 4
  int bx = blockIdx.y;   // 512
  int lane = tid & 63, wave = tid >> 6;
  int wm = wave >> 1, wn = wave & 1;
  int l15 = lane & 15, l4 = lane >> 4;
  const char* wbase = (const char*)Wf + (size_t)layer * 32 * 8192;
#pragma unroll
  for (int i = 0; i < 16; i++) {
    int tt = i >> 1, hh2 = i & 1;
    int ot = (tt < 4) ? (nb * 4 + tt) : (16 + nb * 4 + (tt - 4));
    ((float4*)wlds)[i * 256 + tid] =
        *(const float4*)(wbase + (size_t)ot * 8192 + hh2 * 4096 + tid * 16);
  }
  __syncthreads();
  int m0 = bx * 128 + wm * 64;
  const char* lb = (const char*)wlds + (size_t)(wn * 2) * 8192 + lane * 16;
  f32x4 acc[4][4] = {};
#pragma unroll 2
  for (int ks = 0; ks < 8; ks++) {
    short8 a[4], bfr[4];
#pragma unroll
    for (int rg = 0; rg < 4; rg++)
      a[rg] = *(const short8*)(Gf + (size_t)(ks * 4 + l4) * 524288 + (size_t)(m0 + rg * 16 + l15) * 8);
#pragma unroll
    for (int ct = 0; ct < 2; ct++) {
      bfr[ct]     = *(const short8*)(lb + ct * 8192 + ks * 1024);
      bfr[ct + 2] = *(const short8*)(lb + (4 + ct) * 8192 + ks * 1024);
    }
#pragma unroll
    for (int rg = 0; rg < 4; rg++)
#pragma unroll
      for (int ct = 0; ct < 4; ct++)
        acc[rg][ct] = __builtin_amdgcn_mfma_f32_16x16x32_bf16(a[rg], bfr[ct], acc[rg][ct], 0, 0, 0);
  }
  int c0 = nb * 64 + wn * 32;
#pragma unroll
  for (int rg = 0; rg < 4; rg++) {
#pragma unroll
    for (int ct = 0; ct < 2; ct++) {
      int j = c0 + ct * 16 + l15;
      float ba = bglu[layer * 512 + j];
      float bg = bglu[layer * 512 + 256 + j];
      f32x4 va = acc[rg][ct], vg = acc[rg][ct + 2];
      int r0 = m0 + rg * 16 + l4 * 4;
      if (LAST) {
#pragma unroll
        for (int r = 0; r < 4; r++) {
          float za = va[r] + ba, zg = vg[r] + bg;
          Xout[(size_t)(r0 + r) * Hn + j] = f2bf(za / (1.0f + expf(-zg)));
        }
      } else {
        int b = r0 >> 11, li = r0 & 2047;
        int c = li >> 6, t0 = li & 63;
        ushort4_t w;
#pragma unroll
        for (int r = 0; r < 4; r++) {
          float za = va[r] + ba, zg = vg[r] + bg;
          w[r] = f2bf(za / (1.0f + expf(-zg)));
        }
        *(ushort4_t*)(Xout + ((size_t)(b * NCn + c) * Hn + j) * Tn + t0) = w;
      }
    }
  }
}

// ---- output projection: (B*L,256) bf16 @ (256,2) + b ----------------------------
__global__ __launch_bounds__(256) void k_outproj(const u16* __restrict__ Xp,
                                                 const float* __restrict__ Wout,
                                                 const float* __restrict__ b_out,
                                                 float* __restrict__ out) {
  int row = blockIdx.x * 4 + (threadIdx.x >> 6);
  int lane = threadIdx.x & 63;
  ushort4_t xv = *(const ushort4_t*)(Xp + (size_t)row * Hn + lane * 4);
  float x0 = bf2f(xv[0]), x1 = bf2f(xv[1]), x2 = bf2f(xv[2]), x3 = bf2f(xv[3]);
  const float4 w01 = *(const float4*)&Wout[lane * 8];
  const float4 w23 = *(const float4*)&Wout[lane * 8 + 4];
  float p0 = x0 * w01.x + x1 * w01.z + x2 * w23.x + x3 * w23.z;
  float p1 = x0 * w01.y + x1 * w01.w + x2 * w23.y + x3 * w23.w;
  for (int off = 32; off; off >>= 1) {
    p0 += __shfl_down(p0, off, 64);
    p1 += __shfl_down(p1, off, 64);
  }
  if (lane == 0) {
    out[(size_t)row * 2 + 0] = p0 + b_out[0];
    out[(size_t)row * 2 + 1] = p1 + b_out[1];
  }
}

extern "C" void kernel_launch(void* const* d_in, const int* in_sizes, int n_in,
                              void* d_out, int out_size, void* d_ws, size_t ws_size,
                              hipStream_t stream) {
  const float* nin        = (const float*)d_in[0];
  const float* Win        = (const float*)d_in[1];
  const float* b_in       = (const float*)d_in[2];
  const float* C2         = (const float*)d_in[3];
  const float* log_dt     = (const float*)d_in[4];
  const float* log_A_real = (const float*)d_in[5];
  const float* A_imag     = (const float*)d_in[6];
  const float* Dp         = (const float*)d_in[7];
  const float* Wglu       = (const float*)d_in[8];
  const float* bglu       = (const float*)d_in[9];
  const float* Wout       = (const float*)d_in[10];
  const float* b_out      = (const float*)d_in[11];
  float* out = (float*)d_out;

  // workspace (bf16 elems unless noted): Xc 16.78M | Gf 16.78M | Af 12.58M |
  // Wt 49K | Wf 524K | Lm/Em/Fm 4.19M x3 | ktab/cAT/cC/cDt 65.5K f32 each  ~120MB
  u16* Xc = (u16*)d_ws;
  u16* Gf = Xc + (size_t)16777216;
  u16* Af = Gf + (size_t)16777216;
  u16* Wt = Af + (size_t)12582912;
  u16* Wf = Wt + (size_t)49152;
  u16* Lm = Wf + (size_t)524288;
  u16* Em = Lm + (size_t)4194304;
  u16* Fm = Em + (size_t)4194304;
  float* ktab = (float*)(Fm + (size_t)4194304);
  float* cAT  = ktab + 65536;
  float* cC   = cAT + 65536;
  float* cDt  = cC + 65536;

  k_consts<<<(NLn * Hn * N2n + 255) / 256, 256, 0, stream>>>(C2, log_dt, log_A_real, A_imag, cAT, cC, cDt);
  k_ktab<<<(NLn * Hn * Tn + 255) / 256, 256, 0, stream>>>(cDt, cC, ktab);
  k_build<<<dim3(Hn, NLn * 3), 256, 0, stream>>>(cDt, cC, ktab, Dp, Lm, Em, Fm);
  k_wf<<<(NLn * 2 * Hn * Hn + 255) / 256, 256, 0, stream>>>(Wglu, Wf);
  k_cvt<<<(Bn * Ln * KP + 255) / 256, 256, 0, stream>>>(nin, Af);
  k_wtin<<<(Hn * KP + 255) / 256, 256, 0, stream>>>(Win, Wt);
  k_inproj<<<dim3(2, 512), 256, 0, stream>>>(Af, Wt, b_in, Xc);
  for (int l = 0; l < NLn; l++) {
    k_s4d<<<dim3(Bn, 32), 256, 0, stream>>>(Xc, Lm, Em, Fm, cAT, Gf, l);
    if (l < NLn - 1)
      k_glu<0><<<dim3(4, 512), 256, 0, stream>>>(Gf, Wf, bglu, Xc, l);
    else
      k_glu<1><<<dim3(4, 512), 256, 0, stream>>>(Gf, Wf, bglu, Xc, l);
  }
  k_outproj<<<Bn * Ln / 4, 256, 0, stream>>>(Xc, Wout, b_out, out);
}

// Round 4
// 572.722 us; speedup vs baseline: 4.2604x; 1.0232x over previous
//
#include <hip/hip_runtime.h>
#include <math.h>

typedef unsigned short u16;
typedef __attribute__((ext_vector_type(2))) unsigned short ushort2_t;
typedef __attribute__((ext_vector_type(4))) unsigned short ushort4_t;
typedef __attribute__((ext_vector_type(8))) unsigned short ushort8_t;
typedef __attribute__((ext_vector_type(8))) short short8;
typedef __attribute__((ext_vector_type(4))) float f32x4;

constexpr int Bn = 32, Ln = 2048, IN_DIM = 182, OUT_DIM = 2;
constexpr int Hn = 256, N2n = 32, NLn = 4;
constexpr int Tn = 64, NCn = Ln / Tn;      // 32 chunks of 64 steps
constexpr int KP = 192;                    // padded K for input proj

__device__ inline u16 f2bf(float f) {
  unsigned int u = __float_as_uint(f);
  u += 0x7fffu + ((u >> 16) & 1u);         // RNE
  return (u16)(u >> 16);
}
__device__ inline float bf2f(u16 v) { return __uint_as_float(((unsigned int)v) << 16); }

// ---- per-layer scalar constants: aT = a^64, C' = 2C(a-1)/A, (dr,di) = dt*A ----
__global__ void k_consts(const float* __restrict__ C2, const float* __restrict__ log_dt,
                         const float* __restrict__ log_A_real, const float* __restrict__ A_imag,
                         float* __restrict__ cAT, float* __restrict__ cC, float* __restrict__ cDt) {
  int idx = blockIdx.x * blockDim.x + threadIdx.x;  // l*H*N2 + h*N2 + n
  if (idx >= NLn * Hn * N2n) return;
  int lh = idx / N2n;
  int h = lh % Hn;
  int l = lh / Hn;
  float dt = expf(log_dt[l * Hn + h]);
  float Ar = -expf(log_A_real[idx]);
  float Ai = A_imag[idx];
  float dr = Ar * dt, di = Ai * dt;
  float ea = expf(dr);
  float ar = ea * cosf(di), ai = ea * sinf(di);
  float eT = expf(dr * (float)Tn);
  cAT[idx * 2 + 0] = eT * cosf(di * (float)Tn);
  cAT[idx * 2 + 1] = eT * sinf(di * (float)Tn);
  float nr = ar - 1.0f, ni = ai;
  float inv = 1.0f / (Ar * Ar + Ai * Ai);
  float qr = (nr * Ar + ni * Ai) * inv;
  float qi = (ni * Ar - nr * Ai) * inv;
  float c2r = C2[idx * 2 + 0], c2i = C2[idx * 2 + 1];
  cC[idx * 2 + 0] = 2.0f * (c2r * qr - c2i * qi);
  cC[idx * 2 + 1] = 2.0f * (c2r * qi + c2i * qr);
  cDt[idx * 2 + 0] = dr;
  cDt[idx * 2 + 1] = di;
}

// ---- k_h[d] = sum_n Re(C'_n a_n^d): power-recurrence + LDS tree reduce ----------
__global__ __launch_bounds__(256) void k_ktab(const float* __restrict__ cDt,
                                              const float* __restrict__ cC,
                                              float* __restrict__ ktab) {
  __shared__ float tmp[32][65];
  __shared__ float part[4][64];
  int lh = blockIdx.x;
  int tid = threadIdx.x;
  int n = tid >> 3, dq = tid & 7;
  float dr = cDt[(lh * N2n + n) * 2 + 0], di = cDt[(lh * N2n + n) * 2 + 1];
  float Cr = cC[(lh * N2n + n) * 2 + 0], Ci = cC[(lh * N2n + n) * 2 + 1];
  float d0 = (float)(dq * 8);
  float e0 = expf(dr * d0);
  float pr = e0 * cosf(di * d0), pi = e0 * sinf(di * d0);
  float ea = expf(dr);
  float ar = ea * cosf(di), ai = ea * sinf(di);
#pragma unroll
  for (int j = 0; j < 8; j++) {
    tmp[n][dq * 8 + j] = Cr * pr - Ci * pi;
    float t = pr * ar - pi * ai;
    pi = pr * ai + pi * ar;
    pr = t;
  }
  __syncthreads();
  int d = tid & 63, q = tid >> 6;
  float s = 0.0f;
#pragma unroll
  for (int k = 0; k < 8; k++) s += tmp[q * 8 + k][d];
  part[q][d] = s;
  __syncthreads();
  if (tid < 64) ktab[lh * 64 + tid] = part[0][tid] + part[1][tid] + part[2][tid] + part[3][tid];
}

// ---- build Lm/Em/Fm 64x64 bf16 matrices per (layer, h) --------------------------
// Lm[t][tau] = (t>=tau) ? k[t-tau] + (t==tau)*D : 0
// Em[2n][tau] = Re(a^(63-tau)), Em[2n+1][tau] = Im(a^(63-tau))
// Fm[t][2n] = Re(C' a^(t+1)),  Fm[t][2n+1] = -Im(C' a^(t+1))
__global__ void k_build(const float* __restrict__ cDt, const float* __restrict__ cC,
                        const float* __restrict__ ktab, const float* __restrict__ Dp,
                        u16* __restrict__ Lm, u16* __restrict__ Em, u16* __restrict__ Fm) {
  int h = blockIdx.x;
  int ym = blockIdx.y;         // l*3 + mat
  int l = ym / 3, mat = ym % 3;
  int tid = threadIdx.x;
  int lh = l * Hn + h;
  if (mat == 2) {              // Fm: thread = (tg, n2); recurrence over t
    int n2 = tid & 31, tg = tid >> 5;
    float dr = cDt[(lh * N2n + n2) * 2 + 0], di = cDt[(lh * N2n + n2) * 2 + 1];
    float Cr = cC[(lh * N2n + n2) * 2 + 0], Ci = cC[(lh * N2n + n2) * 2 + 1];
    float p0 = (float)(tg * 8 + 1);
    float e0 = expf(dr * p0);
    float pr = e0 * cosf(di * p0), pi = e0 * sinf(di * p0);
    float ea = expf(dr);
    float ar = ea * cosf(di), ai = ea * sinf(di);
#pragma unroll
    for (int j = 0; j < 8; j++) {
      float wr = Cr * pr - Ci * pi;
      float wi = Cr * pi + Ci * pr;
      ushort2_t o; o[0] = f2bf(wr); o[1] = f2bf(-wi);
      *(ushort2_t*)(Fm + (size_t)lh * 4096 + (tg * 8 + j) * 64 + n2 * 2) = o;
      float t = pr * ar - pi * ai;
      pi = pr * ai + pi * ar;
      pr = t;
    }
    return;
  }
  int row = tid >> 2, tq = (tid & 3) * 16;
  u16 vals[16];
  if (mat == 0) {
    float Dh = Dp[lh];
    for (int j = 0; j < 16; j++) {
      int tau = tq + j;
      int d = row - tau;
      float v = 0.0f;
      if (d >= 0) { v = ktab[lh * 64 + d]; if (d == 0) v += Dh; }
      vals[j] = f2bf(v);
    }
  } else {                     // Em: recurrence ascending power, j descending
    int n = row >> 1, im = row & 1;
    float dr = cDt[(lh * N2n + n) * 2 + 0], di = cDt[(lh * N2n + n) * 2 + 1];
    float p0 = (float)(48 - tq);
    float e0 = expf(dr * p0);
    float pr = e0 * cosf(di * p0), pi = e0 * sinf(di * p0);
    float ea = expf(dr);
    float ar = ea * cosf(di), ai = ea * sinf(di);
#pragma unroll
    for (int j = 15; j >= 0; j--) {
      vals[j] = f2bf(im ? pi : pr);
      float t = pr * ar - pi * ai;
      pi = pr * ai + pi * ar;
      pr = t;
    }
  }
  u16* dst = (mat == 0 ? Lm : Em) + (size_t)lh * 4096 + row * 64 + tq;
  ushort8_t o0, o1;
  for (int j = 0; j < 8; j++) { o0[j] = vals[j]; o1[j] = vals[8 + j]; }
  *(ushort8_t*)dst = o0;
  *(ushort8_t*)(dst + 8) = o1;
}

// ---- Wglu (l,o,k) fp32 -> Wf bf16 frag layout [l][o/16][k/8][16][8] -------------
__global__ void k_wf(const float* __restrict__ Wglu, u16* __restrict__ Wf) {
  int idx = blockIdx.x * blockDim.x + threadIdx.x;  // l*512*256 + o*256 + k
  if (idx >= NLn * 2 * Hn * Hn) return;
  int k = idx & 255;
  int o = (idx >> 8) & 511;
  int l = idx >> 17;
  size_t off = (size_t)l * (32 * 8192) + (size_t)(o >> 4) * 8192
             + (size_t)(k >> 3) * 256 + (o & 15) * 16 + (k & 7) * 2;
  *(u16*)((char*)Wf + off) = f2bf(Wglu[idx]);
}

// ---- nin fp32 (m,182) -> Af bf16 [m][192] (zero pad) ----------------------------
__global__ void k_cvt(const float* __restrict__ nin, u16* __restrict__ Af) {
  int idx = blockIdx.x * blockDim.x + threadIdx.x;
  if (idx >= Bn * Ln * KP) return;
  int m = idx / KP, k = idx - m * KP;
  Af[idx] = (k < IN_DIM) ? f2bf(nin[(size_t)m * IN_DIM + k]) : (u16)0;
}

// ---- Win fp32 (182,256) -> Wt bf16 [h][192] -------------------------------------
__global__ void k_wtin(const float* __restrict__ Win, u16* __restrict__ Wt) {
  int idx = blockIdx.x * blockDim.x + threadIdx.x;
  if (idx >= Hn * KP) return;
  int h = idx / KP, k = idx - h * KP;
  Wt[idx] = (k < IN_DIM) ? f2bf(Win[(size_t)k * Hn + h]) : (u16)0;
}

// ---- input projection via MFMA -> X_c[b][c][h][t] bf16 --------------------------
__global__ __launch_bounds__(256) void k_inproj(const u16* __restrict__ Af,
                                                const u16* __restrict__ Wt,
                                                const float* __restrict__ b_in,
                                                u16* __restrict__ Xc) {
  int tid = threadIdx.x;
  int bx = blockIdx.x;   // 512 (fastest -> both nb of one bx on same XCD)
  int nb = blockIdx.y;   // 2
  int lane = tid & 63, wave = tid >> 6;
  int wm = wave >> 1, wn = wave & 1;
  int l15 = lane & 15, l4 = lane >> 4;
  int m0 = bx * 128 + wm * 64;
  int h0 = nb * 128 + wn * 64;
  f32x4 acc[4][4] = {};
#pragma unroll 2
  for (int ks = 0; ks < 6; ks++) {
    short8 a[4], bfr[4];
#pragma unroll
    for (int mt = 0; mt < 4; mt++)
      a[mt] = *(const short8*)(Af + (size_t)(m0 + mt * 16 + l15) * KP + ks * 32 + l4 * 8);
#pragma unroll
    for (int nt = 0; nt < 4; nt++)
      bfr[nt] = *(const short8*)(Wt + (size_t)(h0 + nt * 16 + l15) * KP + ks * 32 + l4 * 8);
#pragma unroll
    for (int mt = 0; mt < 4; mt++)
#pragma unroll
      for (int nt = 0; nt < 4; nt++)
        acc[mt][nt] = __builtin_amdgcn_mfma_f32_16x16x32_bf16(a[mt], bfr[nt], acc[mt][nt], 0, 0, 0);
  }
#pragma unroll
  for (int mt = 0; mt < 4; mt++) {
#pragma unroll
    for (int nt = 0; nt < 4; nt++) {
      int j = h0 + nt * 16 + l15;
      float bb = b_in[j];
      int r0 = m0 + mt * 16 + l4 * 4;
      int b = r0 >> 11, li = r0 & 2047;
      int c = li >> 6, t0 = li & 63;
      ushort4_t w;
#pragma unroll
      for (int r = 0; r < 4; r++) w[r] = f2bf(acc[mt][nt][r] + bb);
      *(ushort4_t*)(Xc + ((size_t)(b * NCn + c) * Hn + j) * Tn + t0) = w;
    }
  }
}

// ---- fused S4D layer: E@U -> carry scan -> L@U + F@carry -> GELU -> Gf planes ---
// Xc[b][c][h][t] bf16 in; Gf[h/8][b][l][8] bf16 out.
__global__ __launch_bounds__(256) void k_s4d(const u16* __restrict__ Xc,
                                             const u16* __restrict__ Lm,
                                             const u16* __restrict__ Em,
                                             const u16* __restrict__ Fm,
                                             const float* __restrict__ cAT,
                                             u16* __restrict__ Gf, int layer) {
  __shared__ __align__(16) char sbuf[32768];  // s_end/carry: [hl8][c32][64 comp bf16], grp XOR (c&7)
  __shared__ __align__(16) char ybuf[16384];  // half-y: [cl16][hl8][16 grp of 8B], grp=(t>>2)^cl
  int tid = threadIdx.x;
  int lane = tid & 63, wave = tid >> 6;
  int l15 = lane & 15, l4 = lane >> 4;
  int hg = blockIdx.x;   // 32 (fastest -> all b of one hg share XCD for Lm/Em/Fm)
  int b = blockIdx.y;    // 32

  short8 ufr[2][2][2];   // [hi][nt][ks]
  // phase A: load u-frags, E@U -> s_end LDS
  for (int hi = 0; hi < 2; hi++) {
    int hl = wave * 2 + hi;
    int h = hg * 8 + hl;
    const u16* xb = Xc + ((size_t)(b * NCn) * Hn + h) * Tn;
#pragma unroll
    for (int nt = 0; nt < 2; nt++)
#pragma unroll
      for (int ks = 0; ks < 2; ks++)
        ufr[hi][nt][ks] = *(const short8*)(xb + (size_t)(nt * 16 + l15) * (Hn * Tn) + ks * 32 + l4 * 8);
    const u16* eb = Em + (size_t)(layer * Hn + h) * 4096;
#pragma unroll
    for (int mt = 0; mt < 4; mt++) {
      f32x4 sacc[2] = {};
#pragma unroll
      for (int ks = 0; ks < 2; ks++) {
        short8 af = *(const short8*)(eb + (mt * 16 + l15) * 64 + ks * 32 + l4 * 8);
#pragma unroll
        for (int nt = 0; nt < 2; nt++)
          sacc[nt] = __builtin_amdgcn_mfma_f32_16x16x32_bf16(af, ufr[hi][nt][ks], sacc[nt], 0, 0, 0);
      }
      int comp0 = mt * 16 + l4 * 4;
      int g = comp0 >> 3, half = (comp0 >> 2) & 1;
#pragma unroll
      for (int nt = 0; nt < 2; nt++) {
        int c = nt * 16 + l15;
        ushort4_t w;
#pragma unroll
        for (int r = 0; r < 4; r++) w[r] = f2bf(sacc[nt][r]);
        *(ushort4_t*)(sbuf + hl * 4096 + c * 128 + (g ^ (c & 7)) * 16 + half * 8) = w;
      }
    }
  }
  __syncthreads();
  // phase B: carry scan, register-pipelined (loads independent, then scan, then store)
  {
    int hl = tid >> 5, n = tid & 31;
    int h = hg * 8 + hl;
    float aTr = cAT[((size_t)(layer * Hn + h) * N2n + n) * 2 + 0];
    float aTi = cAT[((size_t)(layer * Hn + h) * N2n + n) * 2 + 1];
    int grp = n >> 2, off = (n & 3) * 4;
    char* base = sbuf + hl * 4096;
    unsigned int sv[NCn];
#pragma unroll
    for (int c = 0; c < NCn; c++)
      sv[c] = *(const unsigned int*)(base + c * 128 + ((grp ^ (c & 7)) << 4) + off);
    float cr = 0.0f, ci = 0.0f;
#pragma unroll
    for (int c = 0; c < NCn; c++) {
      unsigned int s = sv[c];
      float sre = bf2f((u16)(s & 0xffffu));
      float sim = bf2f((u16)(s >> 16));
      sv[c] = (unsigned int)f2bf(cr) | ((unsigned int)f2bf(ci) << 16);  // carry-IN
      float nr = aTr * cr - aTi * ci + sre;
      float ni = aTr * ci + aTi * cr + sim;
      cr = nr; ci = ni;
    }
#pragma unroll
    for (int c = 0; c < NCn; c++)
      *(unsigned int*)(base + c * 128 + ((grp ^ (c & 7)) << 4) + off) = sv[c];
  }
  __syncthreads();
  // phase C/D: nt-split halves (ybuf 16 KB reused)
  u16* gp = Gf + (size_t)(hg * Bn + b) * Ln * 8;
  for (int nt = 0; nt < 2; nt++) {
    for (int hi = 0; hi < 2; hi++) {
      int hl = wave * 2 + hi;
      int h = hg * 8 + hl;
      const u16* lb = Lm + (size_t)(layer * Hn + h) * 4096;
      const u16* fb = Fm + (size_t)(layer * Hn + h) * 4096;
      int c = nt * 16 + l15;
#pragma unroll
      for (int mt = 0; mt < 4; mt++) {
        f32x4 yacc = {};
#pragma unroll
        for (int ks = 0; ks < 2; ks++) {
          short8 af = *(const short8*)(lb + (mt * 16 + l15) * 64 + ks * 32 + l4 * 8);
          yacc = __builtin_amdgcn_mfma_f32_16x16x32_bf16(af, ufr[hi][nt][ks], yacc, 0, 0, 0);
        }
#pragma unroll
        for (int ks = 0; ks < 2; ks++) {
          short8 af = *(const short8*)(fb + (mt * 16 + l15) * 64 + ks * 32 + l4 * 8);
          short8 bf = *(const short8*)(sbuf + hl * 4096 + c * 128 + (((ks * 4 + l4) ^ (c & 7)) << 4));
          yacc = __builtin_amdgcn_mfma_f32_16x16x32_bf16(af, bf, yacc, 0, 0, 0);
        }
        int t0 = mt * 16 + l4 * 4;
        ushort4_t w;
#pragma unroll
        for (int r = 0; r < 4; r++) {
          float y = yacc[r];
          w[r] = f2bf(0.5f * y * (1.0f + erff(y * 0.70710678118654752f)));
        }
        int g = ((t0 >> 2) ^ l15) & 15;
        *(ushort4_t*)(ybuf + (l15 * 8 + hl) * 128 + g * 8) = w;
      }
    }
    __syncthreads();
    // phase D half: 1024 m-rows (c in [nt*16, nt*16+16))
#pragma unroll
    for (int it = 0; it < 4; it++) {
      int mloc = it * 256 + tid;
      int cl = mloc >> 6, t = mloc & 63;
      int g = ((t >> 2) ^ cl) & 15;
      const char* bb = ybuf + (cl * 8) * 128 + g * 8 + (t & 3) * 2;
      ushort8_t o;
#pragma unroll
      for (int hl = 0; hl < 8; hl++) o[hl] = *(const u16*)(bb + hl * 128);
      int m = (nt * 16 + cl) * 64 + t;
      *(ushort8_t*)(gp + (size_t)m * 8) = o;
    }
    __syncthreads();
  }
}

// ---- GLU via MFMA: A from Gf planes, B direct from L2-resident Wf frags ---------
template <int LAST>
__global__ __launch_bounds__(256) void k_glu(const u16* __restrict__ Gf,
                                             const u16* __restrict__ Wf,
                                             const float* __restrict__ bglu,
                                             u16* __restrict__ Xout, int layer) {
  int tid = threadIdx.x;
  int bx = blockIdx.x;   // 512 (fastest -> the 4 nb-copies of one bx share an XCD)
  int nb = blockIdx.y;   // 4
  int lane = tid & 63, wave = tid >> 6;
  int wm = wave >> 1, wn = wave & 1;
  int l15 = lane & 15, l4 = lane >> 4;
  int m0 = bx * 128 + wm * 64;
  const char* wb = (const char*)Wf + (size_t)layer * 262144 + lane * 16;
  f32x4 acc[4][4] = {};
#pragma unroll 2
  for (int ks = 0; ks < 8; ks++) {
    short8 a[4], bfr[4];
#pragma unroll
    for (int rg = 0; rg < 4; rg++)
      a[rg] = *(const short8*)(Gf + (size_t)(ks * 4 + l4) * 524288 + (size_t)(m0 + rg * 16 + l15) * 8);
#pragma unroll
    for (int ct = 0; ct < 2; ct++) {
      bfr[ct]     = *(const short8*)(wb + (size_t)(nb * 4 + wn * 2 + ct) * 8192 + ks * 1024);
      bfr[ct + 2] = *(const short8*)(wb + (size_t)(16 + nb * 4 + wn * 2 + ct) * 8192 + ks * 1024);
    }
#pragma unroll
    for (int rg = 0; rg < 4; rg++)
#pragma unroll
      for (int ct = 0; ct < 4; ct++)
        acc[rg][ct] = __builtin_amdgcn_mfma_f32_16x16x32_bf16(a[rg], bfr[ct], acc[rg][ct], 0, 0, 0);
  }
  int c0 = nb * 64 + wn * 32;
#pragma unroll
  for (int rg = 0; rg < 4; rg++) {
#pragma unroll
    for (int ct = 0; ct < 2; ct++) {
      int j = c0 + ct * 16 + l15;
      float ba = bglu[layer * 512 + j];
      float bg = bglu[layer * 512 + 256 + j];
      f32x4 va = acc[rg][ct], vg = acc[rg][ct + 2];
      int r0 = m0 + rg * 16 + l4 * 4;
      if (LAST) {
#pragma unroll
        for (int r = 0; r < 4; r++) {
          float za = va[r] + ba, zg = vg[r] + bg;
          Xout[(size_t)(r0 + r) * Hn + j] = f2bf(za / (1.0f + expf(-zg)));
        }
      } else {
        int b = r0 >> 11, li = r0 & 2047;
        int c = li >> 6, t0 = li & 63;
        ushort4_t w;
#pragma unroll
        for (int r = 0; r < 4; r++) {
          float za = va[r] + ba, zg = vg[r] + bg;
          w[r] = f2bf(za / (1.0f + expf(-zg)));
        }
        *(ushort4_t*)(Xout + ((size_t)(b * NCn + c) * Hn + j) * Tn + t0) = w;
      }
    }
  }
}

// ---- output projection: (B*L,256) bf16 @ (256,2) + b ----------------------------
__global__ __launch_bounds__(256) void k_outproj(const u16* __restrict__ Xp,
                                                 const float* __restrict__ Wout,
                                                 const float* __restrict__ b_out,
                                                 float* __restrict__ out) {
  int row = blockIdx.x * 4 + (threadIdx.x >> 6);
  int lane = threadIdx.x & 63;
  ushort4_t xv = *(const ushort4_t*)(Xp + (size_t)row * Hn + lane * 4);
  float x0 = bf2f(xv[0]), x1 = bf2f(xv[1]), x2 = bf2f(xv[2]), x3 = bf2f(xv[3]);
  const float4 w01 = *(const float4*)&Wout[lane * 8];
  const float4 w23 = *(const float4*)&Wout[lane * 8 + 4];
  float p0 = x0 * w01.x + x1 * w01.z + x2 * w23.x + x3 * w23.z;
  float p1 = x0 * w01.y + x1 * w01.w + x2 * w23.y + x3 * w23.w;
  for (int off = 32; off; off >>= 1) {
    p0 += __shfl_down(p0, off, 64);
    p1 += __shfl_down(p1, off, 64);
  }
  if (lane == 0) {
    out[(size_t)row * 2 + 0] = p0 + b_out[0];
    out[(size_t)row * 2 + 1] = p1 + b_out[1];
  }
}

extern "C" void kernel_launch(void* const* d_in, const int* in_sizes, int n_in,
                              void* d_out, int out_size, void* d_ws, size_t ws_size,
                              hipStream_t stream) {
  const float* nin        = (const float*)d_in[0];
  const float* Win        = (const float*)d_in[1];
  const float* b_in       = (const float*)d_in[2];
  const float* C2         = (const float*)d_in[3];
  const float* log_dt     = (const float*)d_in[4];
  const float* log_A_real = (const float*)d_in[5];
  const float* A_imag     = (const float*)d_in[6];
  const float* Dp         = (const float*)d_in[7];
  const float* Wglu       = (const float*)d_in[8];
  const float* bglu       = (const float*)d_in[9];
  const float* Wout       = (const float*)d_in[10];
  const float* b_out      = (const float*)d_in[11];
  float* out = (float*)d_out;

  u16* Xc = (u16*)d_ws;
  u16* Gf = Xc + (size_t)16777216;
  u16* Af = Gf + (size_t)16777216;
  u16* Wt = Af + (size_t)12582912;
  u16* Wf = Wt + (size_t)49152;
  u16* Lm = Wf + (size_t)524288;
  u16* Em = Lm + (size_t)4194304;
  u16* Fm = Em + (size_t)4194304;
  float* ktab = (float*)(Fm + (size_t)4194304);
  float* cAT  = ktab + 65536;
  float* cC   = cAT + 65536;
  float* cDt  = cC + 65536;

  k_consts<<<(NLn * Hn * N2n + 255) / 256, 256, 0, stream>>>(C2, log_dt, log_A_real, A_imag, cAT, cC, cDt);
  k_ktab<<<NLn * Hn, 256, 0, stream>>>(cDt, cC, ktab);
  k_build<<<dim3(Hn, NLn * 3), 256, 0, stream>>>(cDt, cC, ktab, Dp, Lm, Em, Fm);
  k_wf<<<(NLn * 2 * Hn * Hn + 255) / 256, 256, 0, stream>>>(Wglu, Wf);
  k_cvt<<<(Bn * Ln * KP + 255) / 256, 256, 0, stream>>>(nin, Af);
  k_wtin<<<(Hn * KP + 255) / 256, 256, 0, stream>>>(Win, Wt);
  k_inproj<<<dim3(512, 2), 256, 0, stream>>>(Af, Wt, b_in, Xc);
  for (int l = 0; l < NLn; l++) {
    k_s4d<<<dim3(32, Bn), 256, 0, stream>>>(Xc, Lm, Em, Fm, cAT, Gf, l);
    if (l < NLn - 1)
      k_glu<0><<<dim3(512, 4), 256, 0, stream>>>(Gf, Wf, bglu, Xc, l);
    else
      k_glu<1><<<dim3(512, 4), 256, 0, stream>>>(Gf, Wf, bglu, Xc, l);
  }
  k_outproj<<<Bn * Ln / 4, 256, 0, stream>>>(Xc, Wout, b_out, out);
}

// Round 5
// 518.448 us; speedup vs baseline: 4.7064x; 1.1047x over previous
//
#include <hip/hip_runtime.h>
#include <math.h>

typedef unsigned short u16;
typedef __attribute__((ext_vector_type(2))) unsigned short ushort2_t;
typedef __attribute__((ext_vector_type(4))) unsigned short ushort4_t;
typedef __attribute__((ext_vector_type(8))) unsigned short ushort8_t;
typedef __attribute__((ext_vector_type(8))) short short8;
typedef __attribute__((ext_vector_type(4))) float f32x4;

constexpr int Bn = 32, Ln = 2048, IN_DIM = 182, OUT_DIM = 2;
constexpr int Hn = 256, N2n = 32, NLn = 4;
constexpr int Tn = 64, NCn = Ln / Tn;      // 32 chunks of 64 steps
constexpr int KP = 192;                    // padded K for input proj

__device__ inline u16 f2bf(float f) {
  unsigned int u = __float_as_uint(f);
  u += 0x7fffu + ((u >> 16) & 1u);         // RNE
  return (u16)(u >> 16);
}
__device__ inline float bf2f(u16 v) { return __uint_as_float(((unsigned int)v) << 16); }

// ---- per-layer scalar constants: aT = a^64, C' = 2C(a-1)/A, (dr,di) = dt*A ----
__global__ void k_consts(const float* __restrict__ C2, const float* __restrict__ log_dt,
                         const float* __restrict__ log_A_real, const float* __restrict__ A_imag,
                         float* __restrict__ cAT, float* __restrict__ cC, float* __restrict__ cDt) {
  int idx = blockIdx.x * blockDim.x + threadIdx.x;  // l*H*N2 + h*N2 + n
  if (idx >= NLn * Hn * N2n) return;
  int lh = idx / N2n;
  int h = lh % Hn;
  int l = lh / Hn;
  float dt = expf(log_dt[l * Hn + h]);
  float Ar = -expf(log_A_real[idx]);
  float Ai = A_imag[idx];
  float dr = Ar * dt, di = Ai * dt;
  float ea = expf(dr);
  float ar = ea * cosf(di), ai = ea * sinf(di);
  float eT = expf(dr * (float)Tn);
  cAT[idx * 2 + 0] = eT * cosf(di * (float)Tn);
  cAT[idx * 2 + 1] = eT * sinf(di * (float)Tn);
  float nr = ar - 1.0f, ni = ai;
  float inv = 1.0f / (Ar * Ar + Ai * Ai);
  float qr = (nr * Ar + ni * Ai) * inv;
  float qi = (ni * Ar - nr * Ai) * inv;
  float c2r = C2[idx * 2 + 0], c2i = C2[idx * 2 + 1];
  cC[idx * 2 + 0] = 2.0f * (c2r * qr - c2i * qi);
  cC[idx * 2 + 1] = 2.0f * (c2r * qi + c2i * qr);
  cDt[idx * 2 + 0] = dr;
  cDt[idx * 2 + 1] = di;
}

// ---- k_h[d] = sum_n Re(C'_n a_n^d): power-recurrence + LDS tree reduce ----------
__global__ __launch_bounds__(256) void k_ktab(const float* __restrict__ cDt,
                                              const float* __restrict__ cC,
                                              float* __restrict__ ktab) {
  __shared__ float tmp[32][65];
  __shared__ float part[4][64];
  int lh = blockIdx.x;
  int tid = threadIdx.x;
  int n = tid >> 3, dq = tid & 7;
  float dr = cDt[(lh * N2n + n) * 2 + 0], di = cDt[(lh * N2n + n) * 2 + 1];
  float Cr = cC[(lh * N2n + n) * 2 + 0], Ci = cC[(lh * N2n + n) * 2 + 1];
  float d0 = (float)(dq * 8);
  float e0 = expf(dr * d0);
  float pr = e0 * cosf(di * d0), pi = e0 * sinf(di * d0);
  float ea = expf(dr);
  float ar = ea * cosf(di), ai = ea * sinf(di);
#pragma unroll
  for (int j = 0; j < 8; j++) {
    tmp[n][dq * 8 + j] = Cr * pr - Ci * pi;
    float t = pr * ar - pi * ai;
    pi = pr * ai + pi * ar;
    pr = t;
  }
  __syncthreads();
  int d = tid & 63, q = tid >> 6;
  float s = 0.0f;
#pragma unroll
  for (int k = 0; k < 8; k++) s += tmp[q * 8 + k][d];
  part[q][d] = s;
  __syncthreads();
  if (tid < 64) ktab[lh * 64 + tid] = part[0][tid] + part[1][tid] + part[2][tid] + part[3][tid];
}

// ---- build Lm/Em/Fm 64x64 bf16 matrices per (layer, h) --------------------------
__global__ void k_build(const float* __restrict__ cDt, const float* __restrict__ cC,
                        const float* __restrict__ ktab, const float* __restrict__ Dp,
                        u16* __restrict__ Lm, u16* __restrict__ Em, u16* __restrict__ Fm) {
  int h = blockIdx.x;
  int ym = blockIdx.y;         // l*3 + mat
  int l = ym / 3, mat = ym % 3;
  int tid = threadIdx.x;
  int lh = l * Hn + h;
  if (mat == 2) {              // Fm: thread = (tg, n2); recurrence over t
    int n2 = tid & 31, tg = tid >> 5;
    float dr = cDt[(lh * N2n + n2) * 2 + 0], di = cDt[(lh * N2n + n2) * 2 + 1];
    float Cr = cC[(lh * N2n + n2) * 2 + 0], Ci = cC[(lh * N2n + n2) * 2 + 1];
    float p0 = (float)(tg * 8 + 1);
    float e0 = expf(dr * p0);
    float pr = e0 * cosf(di * p0), pi = e0 * sinf(di * p0);
    float ea = expf(dr);
    float ar = ea * cosf(di), ai = ea * sinf(di);
#pragma unroll
    for (int j = 0; j < 8; j++) {
      float wr = Cr * pr - Ci * pi;
      float wi = Cr * pi + Ci * pr;
      ushort2_t o; o[0] = f2bf(wr); o[1] = f2bf(-wi);
      *(ushort2_t*)(Fm + (size_t)lh * 4096 + (tg * 8 + j) * 64 + n2 * 2) = o;
      float t = pr * ar - pi * ai;
      pi = pr * ai + pi * ar;
      pr = t;
    }
    return;
  }
  int row = tid >> 2, tq = (tid & 3) * 16;
  u16 vals[16];
  if (mat == 0) {
    float Dh = Dp[lh];
    for (int j = 0; j < 16; j++) {
      int tau = tq + j;
      int d = row - tau;
      float v = 0.0f;
      if (d >= 0) { v = ktab[lh * 64 + d]; if (d == 0) v += Dh; }
      vals[j] = f2bf(v);
    }
  } else {                     // Em
    int n = row >> 1, im = row & 1;
    float dr = cDt[(lh * N2n + n) * 2 + 0], di = cDt[(lh * N2n + n) * 2 + 1];
    float p0 = (float)(48 - tq);
    float e0 = expf(dr * p0);
    float pr = e0 * cosf(di * p0), pi = e0 * sinf(di * p0);
    float ea = expf(dr);
    float ar = ea * cosf(di), ai = ea * sinf(di);
#pragma unroll
    for (int j = 15; j >= 0; j--) {
      vals[j] = f2bf(im ? pi : pr);
      float t = pr * ar - pi * ai;
      pi = pr * ai + pi * ar;
      pr = t;
    }
  }
  u16* dst = (mat == 0 ? Lm : Em) + (size_t)lh * 4096 + row * 64 + tq;
  ushort8_t o0, o1;
  for (int j = 0; j < 8; j++) { o0[j] = vals[j]; o1[j] = vals[8 + j]; }
  *(ushort8_t*)dst = o0;
  *(ushort8_t*)(dst + 8) = o1;
}

// ---- Wglu (l,o,k) fp32 -> Wf bf16 frag layout [l][o/16][k/8][16][8] -------------
__global__ void k_wf(const float* __restrict__ Wglu, u16* __restrict__ Wf) {
  int idx = blockIdx.x * blockDim.x + threadIdx.x;  // l*512*256 + o*256 + k
  if (idx >= NLn * 2 * Hn * Hn) return;
  int k = idx & 255;
  int o = (idx >> 8) & 511;
  int l = idx >> 17;
  size_t off = (size_t)l * (32 * 8192) + (size_t)(o >> 4) * 8192
             + (size_t)(k >> 3) * 256 + (o & 15) * 16 + (k & 7) * 2;
  *(u16*)((char*)Wf + off) = f2bf(Wglu[idx]);
}

// ---- Win fp32 (182,256) -> Wt bf16 [h][192] -------------------------------------
__global__ void k_wtin(const float* __restrict__ Win, u16* __restrict__ Wt) {
  int idx = blockIdx.x * blockDim.x + threadIdx.x;
  if (idx >= Hn * KP) return;
  int h = idx / KP, k = idx - h * KP;
  Wt[idx] = (k < IN_DIM) ? f2bf(Win[(size_t)k * Hn + h]) : (u16)0;
}

// ---- input projection via MFMA, fused fp32->bf16 A conversion -------------------
__global__ __launch_bounds__(256) void k_inproj(const float* __restrict__ nin,
                                                const u16* __restrict__ Wt,
                                                const float* __restrict__ b_in,
                                                u16* __restrict__ Xc) {
  int tid = threadIdx.x;
  int bx = blockIdx.x;   // 512 (fastest)
  int nb = blockIdx.y;   // 2
  int lane = tid & 63, wave = tid >> 6;
  int wm = wave >> 1, wn = wave & 1;
  int l15 = lane & 15, l4 = lane >> 4;
  int m0 = bx * 128 + wm * 64;
  int h0 = nb * 128 + wn * 64;
  f32x4 acc[4][4] = {};
#pragma unroll
  for (int ks = 0; ks < 6; ks++) {
    int k0 = ks * 32 + l4 * 8;
    short8 a[4], bfr[4];
#pragma unroll
    for (int mt = 0; mt < 4; mt++) {
      const float* rp = nin + (size_t)(m0 + mt * 16 + l15) * IN_DIM + k0;
      short8 v;
      if (k0 + 8 <= IN_DIM) {   // rp is 8B-aligned (182 even, k0 mult of 8)
        float2 f0 = *(const float2*)(rp);
        float2 f1 = *(const float2*)(rp + 2);
        float2 f2 = *(const float2*)(rp + 4);
        float2 f3 = *(const float2*)(rp + 6);
        v[0] = (short)f2bf(f0.x); v[1] = (short)f2bf(f0.y);
        v[2] = (short)f2bf(f1.x); v[3] = (short)f2bf(f1.y);
        v[4] = (short)f2bf(f2.x); v[5] = (short)f2bf(f2.y);
        v[6] = (short)f2bf(f3.x); v[7] = (short)f2bf(f3.y);
      } else {
#pragma unroll
        for (int j = 0; j < 8; j++) {
          int k = k0 + j;
          float x = (k < IN_DIM) ? rp[j] : 0.0f;
          v[j] = (short)f2bf(x);
        }
      }
      a[mt] = v;
    }
#pragma unroll
    for (int nt = 0; nt < 4; nt++)
      bfr[nt] = *(const short8*)(Wt + (size_t)(h0 + nt * 16 + l15) * KP + k0);
#pragma unroll
    for (int mt = 0; mt < 4; mt++)
#pragma unroll
      for (int nt = 0; nt < 4; nt++)
        acc[mt][nt] = __builtin_amdgcn_mfma_f32_16x16x32_bf16(a[mt], bfr[nt], acc[mt][nt], 0, 0, 0);
  }
#pragma unroll
  for (int mt = 0; mt < 4; mt++) {
#pragma unroll
    for (int nt = 0; nt < 4; nt++) {
      int j = h0 + nt * 16 + l15;
      float bb = b_in[j];
      int r0 = m0 + mt * 16 + l4 * 4;
      int b = r0 >> 11, li = r0 & 2047;
      int c = li >> 6, t0 = li & 63;
      ushort4_t w;
#pragma unroll
      for (int r = 0; r < 4; r++) w[r] = f2bf(acc[mt][nt][r] + bb);
      *(ushort4_t*)(Xc + ((size_t)(b * NCn + c) * Hn + j) * Tn + t0) = w;
    }
  }
}

// ---- fused S4D layer, 8 waves / one h per wave ----------------------------------
// Xc[b][c][h][t] bf16 in; Gf[h/8][b][l][8] bf16 out.
__global__ __launch_bounds__(512, 6) void k_s4d(const u16* __restrict__ Xc,
                                                const u16* __restrict__ Lm,
                                                const u16* __restrict__ Em,
                                                const u16* __restrict__ Fm,
                                                const float* __restrict__ cAT,
                                                u16* __restrict__ Gf, int layer) {
  __shared__ __align__(16) char sbuf[32768];  // s_end/carry: [h8][c32][64 comp bf16], grp XOR (c&7)
  __shared__ __align__(16) char ybuf[16384];  // half-y: [cl16][h8][16 grp of 8B], grp=(t>>2)^cl
  int tid = threadIdx.x;
  int lane = tid & 63, w = tid >> 6;          // wave w owns h = hg*8 + w
  int l15 = lane & 15, l4 = lane >> 4;
  int hg = blockIdx.x;   // 32 (same-hg blocks land on same XCD: ids differ by 32)
  int b = blockIdx.y;    // 32
  int h = hg * 8 + w;

  // phase A: load u-frags, E@U -> s_end LDS
  short8 ufr[2][2];   // [nt][ks]
  const u16* xb = Xc + ((size_t)(b * NCn) * Hn + h) * Tn;
#pragma unroll
  for (int nt = 0; nt < 2; nt++)
#pragma unroll
    for (int ks = 0; ks < 2; ks++)
      ufr[nt][ks] = *(const short8*)(xb + (size_t)(nt * 16 + l15) * (Hn * Tn) + ks * 32 + l4 * 8);
  const u16* eb = Em + (size_t)(layer * Hn + h) * 4096;
#pragma unroll
  for (int mt = 0; mt < 4; mt++) {
    f32x4 sacc[2] = {};
#pragma unroll
    for (int ks = 0; ks < 2; ks++) {
      short8 af = *(const short8*)(eb + (mt * 16 + l15) * 64 + ks * 32 + l4 * 8);
#pragma unroll
      for (int nt = 0; nt < 2; nt++)
        sacc[nt] = __builtin_amdgcn_mfma_f32_16x16x32_bf16(af, ufr[nt][ks], sacc[nt], 0, 0, 0);
    }
    int comp0 = mt * 16 + l4 * 4;
    int g = comp0 >> 3, half = (comp0 >> 2) & 1;
#pragma unroll
    for (int nt = 0; nt < 2; nt++) {
      int c = nt * 16 + l15;
      ushort4_t wv;
#pragma unroll
      for (int r = 0; r < 4; r++) wv[r] = f2bf(sacc[nt][r]);
      *(ushort4_t*)(sbuf + w * 4096 + c * 128 + ((g ^ (c & 7)) << 4) + half * 8) = wv;
    }
  }
  __syncthreads();
  // phase B: carry scan (256 threads; 4 passes of 8 chunks in regs)
  if (tid < 256) {
    int hl = tid >> 5, n = tid & 31;
    int hh = hg * 8 + hl;
    float aTr = cAT[((size_t)(layer * Hn + hh) * N2n + n) * 2 + 0];
    float aTi = cAT[((size_t)(layer * Hn + hh) * N2n + n) * 2 + 1];
    int grp = n >> 2, off = (n & 3) * 4;
    char* base = sbuf + hl * 4096;
    float cr = 0.0f, ci = 0.0f;
#pragma unroll
    for (int p = 0; p < 4; p++) {
      unsigned int sv[8];
#pragma unroll
      for (int q = 0; q < 8; q++) {
        int c = p * 8 + q;
        sv[q] = *(const unsigned int*)(base + c * 128 + ((grp ^ (c & 7)) << 4) + off);
      }
#pragma unroll
      for (int q = 0; q < 8; q++) {
        unsigned int s = sv[q];
        float sre = bf2f((u16)(s & 0xffffu));
        float sim = bf2f((u16)(s >> 16));
        sv[q] = (unsigned int)f2bf(cr) | ((unsigned int)f2bf(ci) << 16);  // carry-IN
        float nr = aTr * cr - aTi * ci + sre;
        float ni = aTr * ci + aTi * cr + sim;
        cr = nr; ci = ni;
      }
#pragma unroll
      for (int q = 0; q < 8; q++) {
        int c = p * 8 + q;
        *(unsigned int*)(base + c * 128 + ((grp ^ (c & 7)) << 4) + off) = sv[q];
      }
    }
  }
  __syncthreads();
  // phase C/D: nt-split halves (ybuf 16 KB reused)
  const u16* lb = Lm + (size_t)(layer * Hn + h) * 4096;
  const u16* fb = Fm + (size_t)(layer * Hn + h) * 4096;
  u16* gp = Gf + (size_t)(hg * Bn + b) * Ln * 8;
  for (int nt = 0; nt < 2; nt++) {
    int c = nt * 16 + l15;
#pragma unroll
    for (int mt = 0; mt < 4; mt++) {
      f32x4 yacc = {};
#pragma unroll
      for (int ks = 0; ks < 2; ks++) {
        short8 af = *(const short8*)(lb + (mt * 16 + l15) * 64 + ks * 32 + l4 * 8);
        yacc = __builtin_amdgcn_mfma_f32_16x16x32_bf16(af, ufr[nt][ks], yacc, 0, 0, 0);
      }
#pragma unroll
      for (int ks = 0; ks < 2; ks++) {
        short8 af = *(const short8*)(fb + (mt * 16 + l15) * 64 + ks * 32 + l4 * 8);
        short8 bf = *(const short8*)(sbuf + w * 4096 + c * 128 + (((ks * 4 + l4) ^ (c & 7)) << 4));
        yacc = __builtin_amdgcn_mfma_f32_16x16x32_bf16(af, bf, yacc, 0, 0, 0);
      }
      int t0 = mt * 16 + l4 * 4;
      ushort4_t wv;
#pragma unroll
      for (int r = 0; r < 4; r++) {
        float y = yacc[r];
        wv[r] = f2bf(0.5f * y * (1.0f + erff(y * 0.70710678118654752f)));
      }
      int g = ((t0 >> 2) ^ l15) & 15;
      *(ushort4_t*)(ybuf + (l15 * 8 + w) * 128 + g * 8) = wv;
    }
    __syncthreads();
    // phase D half: 1024 m-rows, 512 threads x 2
#pragma unroll
    for (int it = 0; it < 2; it++) {
      int mloc = it * 512 + tid;
      int cl = mloc >> 6, t = mloc & 63;
      int g = ((t >> 2) ^ cl) & 15;
      const char* bb = ybuf + (cl * 8) * 128 + g * 8 + (t & 3) * 2;
      ushort8_t o;
#pragma unroll
      for (int hl = 0; hl < 8; hl++) o[hl] = *(const u16*)(bb + hl * 128);
      int m = (nt * 16 + cl) * 64 + t;
      *(ushort8_t*)(gp + (size_t)m * 8) = o;
    }
    __syncthreads();
  }
}

// ---- GLU via MFMA: A from Gf planes, B direct from L2-resident Wf frags ---------
template <int LAST>
__global__ __launch_bounds__(256) void k_glu(const u16* __restrict__ Gf,
                                             const u16* __restrict__ Wf,
                                             const float* __restrict__ bglu,
                                             u16* __restrict__ Xout, int layer) {
  int tid = threadIdx.x;
  int bx = blockIdx.x;   // 512 (fastest -> the 4 nb-copies of one bx share an XCD)
  int nb = blockIdx.y;   // 4
  int lane = tid & 63, wave = tid >> 6;
  int wm = wave >> 1, wn = wave & 1;
  int l15 = lane & 15, l4 = lane >> 4;
  int m0 = bx * 128 + wm * 64;
  const char* wb = (const char*)Wf + (size_t)layer * 262144 + lane * 16;
  f32x4 acc[4][4] = {};
#pragma unroll 2
  for (int ks = 0; ks < 8; ks++) {
    short8 a[4], bfr[4];
#pragma unroll
    for (int rg = 0; rg < 4; rg++)
      a[rg] = *(const short8*)(Gf + (size_t)(ks * 4 + l4) * 524288 + (size_t)(m0 + rg * 16 + l15) * 8);
#pragma unroll
    for (int ct = 0; ct < 2; ct++) {
      bfr[ct]     = *(const short8*)(wb + (size_t)(nb * 4 + wn * 2 + ct) * 8192 + ks * 1024);
      bfr[ct + 2] = *(const short8*)(wb + (size_t)(16 + nb * 4 + wn * 2 + ct) * 8192 + ks * 1024);
    }
#pragma unroll
    for (int rg = 0; rg < 4; rg++)
#pragma unroll
      for (int ct = 0; ct < 4; ct++)
        acc[rg][ct] = __builtin_amdgcn_mfma_f32_16x16x32_bf16(a[rg], bfr[ct], acc[rg][ct], 0, 0, 0);
  }
  int c0 = nb * 64 + wn * 32;
#pragma unroll
  for (int rg = 0; rg < 4; rg++) {
#pragma unroll
    for (int ct = 0; ct < 2; ct++) {
      int j = c0 + ct * 16 + l15;
      float ba = bglu[layer * 512 + j];
      float bg = bglu[layer * 512 + 256 + j];
      f32x4 va = acc[rg][ct], vg = acc[rg][ct + 2];
      int r0 = m0 + rg * 16 + l4 * 4;
      if (LAST) {
#pragma unroll
        for (int r = 0; r < 4; r++) {
          float za = va[r] + ba, zg = vg[r] + bg;
          Xout[(size_t)(r0 + r) * Hn + j] = f2bf(za / (1.0f + expf(-zg)));
        }
      } else {
        int b = r0 >> 11, li = r0 & 2047;
        int c = li >> 6, t0 = li & 63;
        ushort4_t w;
#pragma unroll
        for (int r = 0; r < 4; r++) {
          float za = va[r] + ba, zg = vg[r] + bg;
          w[r] = f2bf(za / (1.0f + expf(-zg)));
        }
        *(ushort4_t*)(Xout + ((size_t)(b * NCn + c) * Hn + j) * Tn + t0) = w;
      }
    }
  }
}

// ---- output projection: (B*L,256) bf16 @ (256,2) + b ----------------------------
__global__ __launch_bounds__(256) void k_outproj(const u16* __restrict__ Xp,
                                                 const float* __restrict__ Wout,
                                                 const float* __restrict__ b_out,
                                                 float* __restrict__ out) {
  int row = blockIdx.x * 4 + (threadIdx.x >> 6);
  int lane = threadIdx.x & 63;
  ushort4_t xv = *(const ushort4_t*)(Xp + (size_t)row * Hn + lane * 4);
  float x0 = bf2f(xv[0]), x1 = bf2f(xv[1]), x2 = bf2f(xv[2]), x3 = bf2f(xv[3]);
  const float4 w01 = *(const float4*)&Wout[lane * 8];
  const float4 w23 = *(const float4*)&Wout[lane * 8 + 4];
  float p0 = x0 * w01.x + x1 * w01.z + x2 * w23.x + x3 * w23.z;
  float p1 = x0 * w01.y + x1 * w01.w + x2 * w23.y + x3 * w23.w;
  for (int off = 32; off; off >>= 1) {
    p0 += __shfl_down(p0, off, 64);
    p1 += __shfl_down(p1, off, 64);
  }
  if (lane == 0) {
    out[(size_t)row * 2 + 0] = p0 + b_out[0];
    out[(size_t)row * 2 + 1] = p1 + b_out[1];
  }
}

extern "C" void kernel_launch(void* const* d_in, const int* in_sizes, int n_in,
                              void* d_out, int out_size, void* d_ws, size_t ws_size,
                              hipStream_t stream) {
  const float* nin        = (const float*)d_in[0];
  const float* Win        = (const float*)d_in[1];
  const float* b_in       = (const float*)d_in[2];
  const float* C2         = (const float*)d_in[3];
  const float* log_dt     = (const float*)d_in[4];
  const float* log_A_real = (const float*)d_in[5];
  const float* A_imag     = (const float*)d_in[6];
  const float* Dp         = (const float*)d_in[7];
  const float* Wglu       = (const float*)d_in[8];
  const float* bglu       = (const float*)d_in[9];
  const float* Wout       = (const float*)d_in[10];
  const float* b_out      = (const float*)d_in[11];
  float* out = (float*)d_out;

  u16* Xc = (u16*)d_ws;
  u16* Gf = Xc + (size_t)16777216;
  u16* Wt = Gf + (size_t)16777216;
  u16* Wf = Wt + (size_t)49152;
  u16* Lm = Wf + (size_t)524288;
  u16* Em = Lm + (size_t)4194304;
  u16* Fm = Em + (size_t)4194304;
  float* ktab = (float*)(Fm + (size_t)4194304);
  float* cAT  = ktab + 65536;
  float* cC   = cAT + 65536;
  float* cDt  = cC + 65536;

  k_consts<<<(NLn * Hn * N2n + 255) / 256, 256, 0, stream>>>(C2, log_dt, log_A_real, A_imag, cAT, cC, cDt);
  k_ktab<<<NLn * Hn, 256, 0, stream>>>(cDt, cC, ktab);
  k_build<<<dim3(Hn, NLn * 3), 256, 0, stream>>>(cDt, cC, ktab, Dp, Lm, Em, Fm);
  k_wf<<<(NLn * 2 * Hn * Hn + 255) / 256, 256, 0, stream>>>(Wglu, Wf);
  k_wtin<<<(Hn * KP + 255) / 256, 256, 0, stream>>>(Win, Wt);
  k_inproj<<<dim3(512, 2), 256, 0, stream>>>(nin, Wt, b_in, Xc);
  for (int l = 0; l < NLn; l++) {
    k_s4d<<<dim3(32, Bn), 512, 0, stream>>>(Xc, Lm, Em, Fm, cAT, Gf, l);
    if (l < NLn - 1)
      k_glu<0><<<dim3(512, 4), 256, 0, stream>>>(Gf, Wf, bglu, Xc, l);
    else
      k_glu<1><<<dim3(512, 4), 256, 0, stream>>>(Gf, Wf, bglu, Xc, l);
  }
  k_outproj<<<Bn * Ln / 4, 256, 0, stream>>>(Xc, Wout, b_out, out);
}

// Round 6
// 496.549 us; speedup vs baseline: 4.9140x; 1.0441x over previous
//
#include <hip/hip_runtime.h>
#include <math.h>

typedef unsigned short u16;
typedef __attribute__((ext_vector_type(2))) unsigned short ushort2_t;
typedef __attribute__((ext_vector_type(4))) unsigned short ushort4_t;
typedef __attribute__((ext_vector_type(8))) unsigned short ushort8_t;
typedef __attribute__((ext_vector_type(8))) short short8;
typedef __attribute__((ext_vector_type(4))) float f32x4;

constexpr int Bn = 32, Ln = 2048, IN_DIM = 182, OUT_DIM = 2;
constexpr int Hn = 256, N2n = 32, NLn = 4;
constexpr int Tn = 64, NCn = Ln / Tn;      // 32 chunks of 64 steps
constexpr int KP = 192;                    // padded K for input proj
constexpr int IPPAD = 200;                 // u16 per LDS row in inproj (bank-spread pad)

__device__ inline u16 f2bf(float f) {
  unsigned int u = __float_as_uint(f);
  u += 0x7fffu + ((u >> 16) & 1u);         // RNE
  return (u16)(u >> 16);
}
__device__ inline float bf2f(u16 v) { return __uint_as_float(((unsigned int)v) << 16); }

// ---- fused setup per (layer,h): consts -> ktab -> Lm/Em/Fm (one block per lh) ---
// Lm[t][tau] = (t>=tau) ? k[t-tau] + (t==tau)*D : 0
// Em[2n][tau] = Re(a^(63-tau)), Em[2n+1][tau] = Im(a^(63-tau))
// Fm[t][2n] = Re(C' a^(t+1)),  Fm[t][2n+1] = -Im(C' a^(t+1))
__global__ __launch_bounds__(256) void k_prep(const float* __restrict__ C2,
                                              const float* __restrict__ log_dt,
                                              const float* __restrict__ log_A_real,
                                              const float* __restrict__ A_imag,
                                              const float* __restrict__ Dp,
                                              float* __restrict__ cAT,
                                              u16* __restrict__ Lm, u16* __restrict__ Em,
                                              u16* __restrict__ Fm) {
  __shared__ float sdr[32], sdi[32], sCr[32], sCi[32];
  __shared__ float tmp[32][65];
  __shared__ float part[4][64];
  __shared__ float kt[64];
  int lh = blockIdx.x;
  int tid = threadIdx.x;
  if (tid < 32) {
    int n = tid;
    int idx = lh * N2n + n;
    float dt = expf(log_dt[lh]);
    float Ar = -expf(log_A_real[idx]);
    float Ai = A_imag[idx];
    float dr = Ar * dt, di = Ai * dt;
    float ea = expf(dr);
    float ar = ea * cosf(di), ai = ea * sinf(di);
    float eT = expf(dr * 64.0f);
    cAT[idx * 2 + 0] = eT * cosf(di * 64.0f);
    cAT[idx * 2 + 1] = eT * sinf(di * 64.0f);
    float nr = ar - 1.0f, ni = ai;
    float inv = 1.0f / (Ar * Ar + Ai * Ai);
    float qr = (nr * Ar + ni * Ai) * inv;
    float qi = (ni * Ar - nr * Ai) * inv;
    float c2r = C2[idx * 2 + 0], c2i = C2[idx * 2 + 1];
    sdr[n] = dr; sdi[n] = di;
    sCr[n] = 2.0f * (c2r * qr - c2i * qi);
    sCi[n] = 2.0f * (c2r * qi + c2i * qr);
  }
  __syncthreads();
  // ktab: k[d] = sum_n Re(C'_n a_n^d), power recurrence per (n, d-octet)
  {
    int n = tid >> 3, dq = tid & 7;
    float dr = sdr[n], di = sdi[n], Cr = sCr[n], Ci = sCi[n];
    float d0 = (float)(dq * 8);
    float e0 = expf(dr * d0);
    float pr = e0 * cosf(di * d0), pi = e0 * sinf(di * d0);
    float ea = expf(dr);
    float ar = ea * cosf(di), ai = ea * sinf(di);
#pragma unroll
    for (int j = 0; j < 8; j++) {
      tmp[n][dq * 8 + j] = Cr * pr - Ci * pi;
      float t = pr * ar - pi * ai;
      pi = pr * ai + pi * ar;
      pr = t;
    }
  }
  __syncthreads();
  {
    int d = tid & 63, q = tid >> 6;
    float s = 0.0f;
#pragma unroll
    for (int k = 0; k < 8; k++) s += tmp[q * 8 + k][d];
    part[q][d] = s;
  }
  __syncthreads();
  if (tid < 64) kt[tid] = part[0][tid] + part[1][tid] + part[2][tid] + part[3][tid];
  __syncthreads();
  // Lm
  {
    int row = tid >> 2, tq = (tid & 3) * 16;
    float Dh = Dp[lh];
    u16 vals[16];
    for (int j = 0; j < 16; j++) {
      int d = row - (tq + j);
      float v = 0.0f;
      if (d >= 0) { v = kt[d]; if (d == 0) v += Dh; }
      vals[j] = f2bf(v);
    }
    u16* dst = Lm + (size_t)lh * 4096 + row * 64 + tq;
    ushort8_t o0, o1;
    for (int j = 0; j < 8; j++) { o0[j] = vals[j]; o1[j] = vals[8 + j]; }
    *(ushort8_t*)dst = o0;
    *(ushort8_t*)(dst + 8) = o1;
  }
  // Em
  {
    int row = tid >> 2, tq = (tid & 3) * 16;
    int n = row >> 1, im = row & 1;
    float dr = sdr[n], di = sdi[n];
    float p0 = (float)(48 - tq);
    float e0 = expf(dr * p0);
    float pr = e0 * cosf(di * p0), pi = e0 * sinf(di * p0);
    float ea = expf(dr);
    float ar = ea * cosf(di), ai = ea * sinf(di);
    u16 vals[16];
#pragma unroll
    for (int j = 15; j >= 0; j--) {
      vals[j] = f2bf(im ? pi : pr);
      float t = pr * ar - pi * ai;
      pi = pr * ai + pi * ar;
      pr = t;
    }
    u16* dst = Em + (size_t)lh * 4096 + row * 64 + tq;
    ushort8_t o0, o1;
    for (int j = 0; j < 8; j++) { o0[j] = vals[j]; o1[j] = vals[8 + j]; }
    *(ushort8_t*)dst = o0;
    *(ushort8_t*)(dst + 8) = o1;
  }
  // Fm
  {
    int n2 = tid & 31, tg = tid >> 5;
    float dr = sdr[n2], di = sdi[n2], Cr = sCr[n2], Ci = sCi[n2];
    float p0 = (float)(tg * 8 + 1);
    float e0 = expf(dr * p0);
    float pr = e0 * cosf(di * p0), pi = e0 * sinf(di * p0);
    float ea = expf(dr);
    float ar = ea * cosf(di), ai = ea * sinf(di);
#pragma unroll
    for (int j = 0; j < 8; j++) {
      float wr = Cr * pr - Ci * pi;
      float wi = Cr * pi + Ci * pr;
      ushort2_t o; o[0] = f2bf(wr); o[1] = f2bf(-wi);
      *(ushort2_t*)(Fm + (size_t)lh * 4096 + (tg * 8 + j) * 64 + n2 * 2) = o;
      float t = pr * ar - pi * ai;
      pi = pr * ai + pi * ar;
      pr = t;
    }
  }
}

// ---- Wglu (l,o,k) fp32 -> Wf bf16 frag layout [l][o/16][k/8][16][8] -------------
__global__ void k_wf(const float* __restrict__ Wglu, u16* __restrict__ Wf) {
  int idx = blockIdx.x * blockDim.x + threadIdx.x;  // l*512*256 + o*256 + k
  if (idx >= NLn * 2 * Hn * Hn) return;
  int k = idx & 255;
  int o = (idx >> 8) & 511;
  int l = idx >> 17;
  size_t off = (size_t)l * (32 * 8192) + (size_t)(o >> 4) * 8192
             + (size_t)(k >> 3) * 256 + (o & 15) * 16 + (k & 7) * 2;
  *(u16*)((char*)Wf + off) = f2bf(Wglu[idx]);
}

// ---- Win fp32 (182,256) -> Wt bf16 [h][192] -------------------------------------
__global__ void k_wtin(const float* __restrict__ Win, u16* __restrict__ Wt) {
  int idx = blockIdx.x * blockDim.x + threadIdx.x;
  if (idx >= Hn * KP) return;
  int h = idx / KP, k = idx - h * KP;
  Wt[idx] = (k < IN_DIM) ? f2bf(Win[(size_t)k * Hn + h]) : (u16)0;
}

// ---- input projection via MFMA, LDS-staged streaming A-tile ---------------------
__global__ __launch_bounds__(256) void k_inproj(const float* __restrict__ nin,
                                                const u16* __restrict__ Wt,
                                                const float* __restrict__ b_in,
                                                u16* __restrict__ Xc) {
  __shared__ __align__(16) u16 at[128 * IPPAD];  // 50 KB
  int tid = threadIdx.x;
  int bx = blockIdx.x;   // 512 (fastest; the 2 nb-copies are 512 apart = co-XCD)
  int nb = blockIdx.y;   // 2
  int m0 = bx * 128;
  // zero pad columns 182..199
  for (int i = tid; i < 128 * (IPPAD - IN_DIM); i += 256) {
    int r = i / (IPPAD - IN_DIM), c = IN_DIM + i - r * (IPPAD - IN_DIM);
    at[r * IPPAD + c] = 0;
  }
  // stream 128 rows x 182 fp32 as pure linear float4 reads; convert to bf16
  const float4* src = (const float4*)(nin + (size_t)m0 * IN_DIM);
  for (int i = tid; i < 128 * IN_DIM / 4; i += 256) {
    float4 v = src[i];
    int e0 = i * 4;
    int r = e0 / IN_DIM;
    int c = e0 - r * IN_DIM;
    float vv[4] = {v.x, v.y, v.z, v.w};
#pragma unroll
    for (int j = 0; j < 4; j++) {
      int rr = r, cc = c + j;
      if (cc >= IN_DIM) { rr++; cc -= IN_DIM; }
      at[rr * IPPAD + cc] = f2bf(vv[j]);
    }
  }
  __syncthreads();
  int lane = tid & 63, wave = tid >> 6;
  int wm = wave >> 1, wn = wave & 1;
  int l15 = lane & 15, l4 = lane >> 4;
  int h0 = nb * 128 + wn * 64;
  f32x4 acc[4][4] = {};
#pragma unroll
  for (int ks = 0; ks < 6; ks++) {
    int k0 = ks * 32 + l4 * 8;
    short8 a[4], bfr[4];
#pragma unroll
    for (int mt = 0; mt < 4; mt++)
      a[mt] = *(const short8*)&at[(wm * 64 + mt * 16 + l15) * IPPAD + k0];
#pragma unroll
    for (int nt = 0; nt < 4; nt++)
      bfr[nt] = *(const short8*)(Wt + (size_t)(h0 + nt * 16 + l15) * KP + k0);
#pragma unroll
    for (int mt = 0; mt < 4; mt++)
#pragma unroll
      for (int nt = 0; nt < 4; nt++)
        acc[mt][nt] = __builtin_amdgcn_mfma_f32_16x16x32_bf16(a[mt], bfr[nt], acc[mt][nt], 0, 0, 0);
  }
#pragma unroll
  for (int mt = 0; mt < 4; mt++) {
#pragma unroll
    for (int nt = 0; nt < 4; nt++) {
      int j = h0 + nt * 16 + l15;
      float bb = b_in[j];
      int r0 = m0 + wm * 64 + mt * 16 + l4 * 4;
      int b = r0 >> 11, li = r0 & 2047;
      int c = li >> 6, t0 = li & 63;
      ushort4_t w;
#pragma unroll
      for (int r = 0; r < 4; r++) w[r] = f2bf(acc[mt][nt][r] + bb);
      *(ushort4_t*)(Xc + ((size_t)(b * NCn + c) * Hn + j) * Tn + t0) = w;
    }
  }
}

// ---- fused S4D layer, 8 waves / one h per wave, XCD-chunked block swizzle -------
// Xc[b][c][h][t] bf16 in; Gf[h/8][b][l][8] bf16 out.
__global__ __launch_bounds__(512, 6) void k_s4d(const u16* __restrict__ Xc,
                                                const u16* __restrict__ Lm,
                                                const u16* __restrict__ Em,
                                                const u16* __restrict__ Fm,
                                                const float* __restrict__ cAT,
                                                u16* __restrict__ Gf, int layer) {
  __shared__ __align__(16) char sbuf[32768];  // s_end/carry: [h8][c32][64 comp bf16], grp XOR (c&7)
  __shared__ __align__(16) char ybuf[16384];  // half-y: [cl16][h8][16 grp of 8B], grp=(t>>2)^cl
  int tid = threadIdx.x;
  int lane = tid & 63, w = tid >> 6;          // wave w owns h = hg*8 + w
  int l15 = lane & 15, l4 = lane >> 4;
  // XCD-chunked bijective swizzle: same-hg blocks contiguous within one XCD
  int flat = blockIdx.x;                      // 0..1023
  int vid = (flat & 7) * 128 + (flat >> 3);
  int hg = vid >> 5;     // 32
  int b = vid & 31;      // 32
  int h = hg * 8 + w;

  // phase A: load u-frags, E@U -> s_end LDS
  short8 ufr[2][2];   // [nt][ks]
  const u16* xb = Xc + ((size_t)(b * NCn) * Hn + h) * Tn;
#pragma unroll
  for (int nt = 0; nt < 2; nt++)
#pragma unroll
    for (int ks = 0; ks < 2; ks++)
      ufr[nt][ks] = *(const short8*)(xb + (size_t)(nt * 16 + l15) * (Hn * Tn) + ks * 32 + l4 * 8);
  const u16* eb = Em + (size_t)(layer * Hn + h) * 4096;
#pragma unroll
  for (int mt = 0; mt < 4; mt++) {
    f32x4 sacc[2] = {};
#pragma unroll
    for (int ks = 0; ks < 2; ks++) {
      short8 af = *(const short8*)(eb + (mt * 16 + l15) * 64 + ks * 32 + l4 * 8);
#pragma unroll
      for (int nt = 0; nt < 2; nt++)
        sacc[nt] = __builtin_amdgcn_mfma_f32_16x16x32_bf16(af, ufr[nt][ks], sacc[nt], 0, 0, 0);
    }
    int comp0 = mt * 16 + l4 * 4;
    int g = comp0 >> 3, half = (comp0 >> 2) & 1;
#pragma unroll
    for (int nt = 0; nt < 2; nt++) {
      int c = nt * 16 + l15;
      ushort4_t wv;
#pragma unroll
      for (int r = 0; r < 4; r++) wv[r] = f2bf(sacc[nt][r]);
      *(ushort4_t*)(sbuf + w * 4096 + c * 128 + ((g ^ (c & 7)) << 4) + half * 8) = wv;
    }
  }
  __syncthreads();
  // phase B: carry scan (256 threads; 4 passes of 8 chunks in regs)
  if (tid < 256) {
    int hl = tid >> 5, n = tid & 31;
    int hh = hg * 8 + hl;
    float aTr = cAT[((size_t)(layer * Hn + hh) * N2n + n) * 2 + 0];
    float aTi = cAT[((size_t)(layer * Hn + hh) * N2n + n) * 2 + 1];
    int grp = n >> 2, off = (n & 3) * 4;
    char* base = sbuf + hl * 4096;
    float cr = 0.0f, ci = 0.0f;
#pragma unroll
    for (int p = 0; p < 4; p++) {
      unsigned int sv[8];
#pragma unroll
      for (int q = 0; q < 8; q++) {
        int c = p * 8 + q;
        sv[q] = *(const unsigned int*)(base + c * 128 + ((grp ^ (c & 7)) << 4) + off);
      }
#pragma unroll
      for (int q = 0; q < 8; q++) {
        unsigned int s = sv[q];
        float sre = bf2f((u16)(s & 0xffffu));
        float sim = bf2f((u16)(s >> 16));
        sv[q] = (unsigned int)f2bf(cr) | ((unsigned int)f2bf(ci) << 16);  // carry-IN
        float nr = aTr * cr - aTi * ci + sre;
        float ni = aTr * ci + aTi * cr + sim;
        cr = nr; ci = ni;
      }
#pragma unroll
      for (int q = 0; q < 8; q++) {
        int c = p * 8 + q;
        *(unsigned int*)(base + c * 128 + ((grp ^ (c & 7)) << 4) + off) = sv[q];
      }
    }
  }
  __syncthreads();
  // phase C/D: nt-split halves (ybuf 16 KB reused)
  const u16* lb = Lm + (size_t)(layer * Hn + h) * 4096;
  const u16* fb = Fm + (size_t)(layer * Hn + h) * 4096;
  u16* gp = Gf + (size_t)(hg * Bn + b) * Ln * 8;
  for (int nt = 0; nt < 2; nt++) {
    int c = nt * 16 + l15;
#pragma unroll
    for (int mt = 0; mt < 4; mt++) {
      f32x4 yacc = {};
#pragma unroll
      for (int ks = 0; ks < 2; ks++) {
        short8 af = *(const short8*)(lb + (mt * 16 + l15) * 64 + ks * 32 + l4 * 8);
        yacc = __builtin_amdgcn_mfma_f32_16x16x32_bf16(af, ufr[nt][ks], yacc, 0, 0, 0);
      }
#pragma unroll
      for (int ks = 0; ks < 2; ks++) {
        short8 af = *(const short8*)(fb + (mt * 16 + l15) * 64 + ks * 32 + l4 * 8);
        short8 bf = *(const short8*)(sbuf + w * 4096 + c * 128 + (((ks * 4 + l4) ^ (c & 7)) << 4));
        yacc = __builtin_amdgcn_mfma_f32_16x16x32_bf16(af, bf, yacc, 0, 0, 0);
      }
      int t0 = mt * 16 + l4 * 4;
      ushort4_t wv;
#pragma unroll
      for (int r = 0; r < 4; r++) {
        float y = yacc[r];
        wv[r] = f2bf(0.5f * y * (1.0f + erff(y * 0.70710678118654752f)));
      }
      int g = ((t0 >> 2) ^ l15) & 15;
      *(ushort4_t*)(ybuf + (l15 * 8 + w) * 128 + g * 8) = wv;
    }
    __syncthreads();
#pragma unroll
    for (int it = 0; it < 2; it++) {
      int mloc = it * 512 + tid;
      int cl = mloc >> 6, t = mloc & 63;
      int g = ((t >> 2) ^ cl) & 15;
      const char* bb = ybuf + (cl * 8) * 128 + g * 8 + (t & 3) * 2;
      ushort8_t o;
#pragma unroll
      for (int hl = 0; hl < 8; hl++) o[hl] = *(const u16*)(bb + hl * 128);
      int m = (nt * 16 + cl) * 64 + t;
      *(ushort8_t*)(gp + (size_t)m * 8) = o;
    }
    __syncthreads();
  }
}

// ---- GLU via MFMA, XCD-chunked swizzle so the 4 nb-copies of a bx co-run --------
template <int LAST>
__global__ __launch_bounds__(256) void k_glu(const u16* __restrict__ Gf,
                                             const u16* __restrict__ Wf,
                                             const float* __restrict__ bglu,
                                             u16* __restrict__ Xout, int layer) {
  int tid = threadIdx.x;
  // bijective XCD-chunk swizzle: vid = xcd*256 + pos; nb fastest within XCD
  int flat = blockIdx.x;                 // 0..2047
  int vid = (flat & 7) * 256 + (flat >> 3);
  int bx = vid >> 2;   // 512
  int nb = vid & 3;    // 4
  int lane = tid & 63, wave = tid >> 6;
  int wm = wave >> 1, wn = wave & 1;
  int l15 = lane & 15, l4 = lane >> 4;
  int m0 = bx * 128 + wm * 64;
  const char* wb = (const char*)Wf + (size_t)layer * 262144 + lane * 16;
  f32x4 acc[4][4] = {};
#pragma unroll 2
  for (int ks = 0; ks < 8; ks++) {
    short8 a[4], bfr[4];
#pragma unroll
    for (int rg = 0; rg < 4; rg++)
      a[rg] = *(const short8*)(Gf + (size_t)(ks * 4 + l4) * 524288 + (size_t)(m0 + rg * 16 + l15) * 8);
#pragma unroll
    for (int ct = 0; ct < 2; ct++) {
      bfr[ct]     = *(const short8*)(wb + (size_t)(nb * 4 + wn * 2 + ct) * 8192 + ks * 1024);
      bfr[ct + 2] = *(const short8*)(wb + (size_t)(16 + nb * 4 + wn * 2 + ct) * 8192 + ks * 1024);
    }
#pragma unroll
    for (int rg = 0; rg < 4; rg++)
#pragma unroll
      for (int ct = 0; ct < 4; ct++)
        acc[rg][ct] = __builtin_amdgcn_mfma_f32_16x16x32_bf16(a[rg], bfr[ct], acc[rg][ct], 0, 0, 0);
  }
  int c0 = nb * 64 + wn * 32;
#pragma unroll
  for (int rg = 0; rg < 4; rg++) {
#pragma unroll
    for (int ct = 0; ct < 2; ct++) {
      int j = c0 + ct * 16 + l15;
      float ba = bglu[layer * 512 + j];
      float bg = bglu[layer * 512 + 256 + j];
      f32x4 va = acc[rg][ct], vg = acc[rg][ct + 2];
      int r0 = m0 + rg * 16 + l4 * 4;
      if (LAST) {
#pragma unroll
        for (int r = 0; r < 4; r++) {
          float za = va[r] + ba, zg = vg[r] + bg;
          Xout[(size_t)(r0 + r) * Hn + j] = f2bf(za / (1.0f + expf(-zg)));
        }
      } else {
        int b = r0 >> 11, li = r0 & 2047;
        int c = li >> 6, t0 = li & 63;
        ushort4_t w;
#pragma unroll
        for (int r = 0; r < 4; r++) {
          float za = va[r] + ba, zg = vg[r] + bg;
          w[r] = f2bf(za / (1.0f + expf(-zg)));
        }
        *(ushort4_t*)(Xout + ((size_t)(b * NCn + c) * Hn + j) * Tn + t0) = w;
      }
    }
  }
}

// ---- output projection: (B*L,256) bf16 @ (256,2) + b ----------------------------
__global__ __launch_bounds__(256) void k_outproj(const u16* __restrict__ Xp,
                                                 const float* __restrict__ Wout,
                                                 const float* __restrict__ b_out,
                                                 float* __restrict__ out) {
  int row = blockIdx.x * 4 + (threadIdx.x >> 6);
  int lane = threadIdx.x & 63;
  ushort4_t xv = *(const ushort4_t*)(Xp + (size_t)row * Hn + lane * 4);
  float x0 = bf2f(xv[0]), x1 = bf2f(xv[1]), x2 = bf2f(xv[2]), x3 = bf2f(xv[3]);
  const float4 w01 = *(const float4*)&Wout[lane * 8];
  const float4 w23 = *(const float4*)&Wout[lane * 8 + 4];
  float p0 = x0 * w01.x + x1 * w01.z + x2 * w23.x + x3 * w23.z;
  float p1 = x0 * w01.y + x1 * w01.w + x2 * w23.y + x3 * w23.w;
  for (int off = 32; off; off >>= 1) {
    p0 += __shfl_down(p0, off, 64);
    p1 += __shfl_down(p1, off, 64);
  }
  if (lane == 0) {
    out[(size_t)row * 2 + 0] = p0 + b_out[0];
    out[(size_t)row * 2 + 1] = p1 + b_out[1];
  }
}

extern "C" void kernel_launch(void* const* d_in, const int* in_sizes, int n_in,
                              void* d_out, int out_size, void* d_ws, size_t ws_size,
                              hipStream_t stream) {
  const float* nin        = (const float*)d_in[0];
  const float* Win        = (const float*)d_in[1];
  const float* b_in       = (const float*)d_in[2];
  const float* C2         = (const float*)d_in[3];
  const float* log_dt     = (const float*)d_in[4];
  const float* log_A_real = (const float*)d_in[5];
  const float* A_imag     = (const float*)d_in[6];
  const float* Dp         = (const float*)d_in[7];
  const float* Wglu       = (const float*)d_in[8];
  const float* bglu       = (const float*)d_in[9];
  const float* Wout       = (const float*)d_in[10];
  const float* b_out      = (const float*)d_in[11];
  float* out = (float*)d_out;

  u16* Xc = (u16*)d_ws;
  u16* Gf = Xc + (size_t)16777216;
  u16* Wt = Gf + (size_t)16777216;
  u16* Wf = Wt + (size_t)49152;
  u16* Lm = Wf + (size_t)524288;
  u16* Em = Lm + (size_t)4194304;
  u16* Fm = Em + (size_t)4194304;
  float* cAT = (float*)(Fm + (size_t)4194304);

  k_prep<<<NLn * Hn, 256, 0, stream>>>(C2, log_dt, log_A_real, A_imag, Dp, cAT, Lm, Em, Fm);
  k_wf<<<(NLn * 2 * Hn * Hn + 255) / 256, 256, 0, stream>>>(Wglu, Wf);
  k_wtin<<<(Hn * KP + 255) / 256, 256, 0, stream>>>(Win, Wt);
  k_inproj<<<dim3(512, 2), 256, 0, stream>>>(nin, Wt, b_in, Xc);
  for (int l = 0; l < NLn; l++) {
    k_s4d<<<1024, 512, 0, stream>>>(Xc, Lm, Em, Fm, cAT, Gf, l);
    if (l < NLn - 1)
      k_glu<0><<<2048, 256, 0, stream>>>(Gf, Wf, bglu, Xc, l);
    else
      k_glu<1><<<2048, 256, 0, stream>>>(Gf, Wf, bglu, Xc, l);
  }
  k_outproj<<<Bn * Ln / 4, 256, 0, stream>>>(Xc, Wout, b_out, out);
}

// Round 7
// 451.501 us; speedup vs baseline: 5.4043x; 1.0998x over previous
//
#include <hip/hip_runtime.h>
#include <math.h>

typedef unsigned short u16;
typedef __attribute__((ext_vector_type(2))) unsigned short ushort2_t;
typedef __attribute__((ext_vector_type(4))) unsigned short ushort4_t;
typedef __attribute__((ext_vector_type(8))) unsigned short ushort8_t;
typedef __attribute__((ext_vector_type(8))) short short8;
typedef __attribute__((ext_vector_type(4))) float f32x4;

constexpr int Bn = 32, Ln = 2048, IN_DIM = 182, OUT_DIM = 2;
constexpr int Hn = 256, N2n = 32, NLn = 4;
constexpr int Tn = 64, NCn = Ln / Tn;      // 32 chunks of 64 steps
constexpr int KP = 192;                    // padded K for input proj

__device__ inline u16 f2bf(float f) {
  unsigned int u = __float_as_uint(f);
  u += 0x7fffu + ((u >> 16) & 1u);         // RNE
  return (u16)(u >> 16);
}
__device__ inline float bf2f(u16 v) { return __uint_as_float(((unsigned int)v) << 16); }

// ---- fused setup per (layer,h): consts -> ktab -> Lm/Em/Fm (one block per lh) ---
__global__ __launch_bounds__(256) void k_prep(const float* __restrict__ C2,
                                              const float* __restrict__ log_dt,
                                              const float* __restrict__ log_A_real,
                                              const float* __restrict__ A_imag,
                                              const float* __restrict__ Dp,
                                              float* __restrict__ cAT,
                                              u16* __restrict__ Lm, u16* __restrict__ Em,
                                              u16* __restrict__ Fm) {
  __shared__ float sdr[32], sdi[32], sCr[32], sCi[32];
  __shared__ float tmp[32][65];
  __shared__ float part[4][64];
  __shared__ float kt[64];
  int lh = blockIdx.x;
  int tid = threadIdx.x;
  if (tid < 32) {
    int n = tid;
    int idx = lh * N2n + n;
    float dt = expf(log_dt[lh]);
    float Ar = -expf(log_A_real[idx]);
    float Ai = A_imag[idx];
    float dr = Ar * dt, di = Ai * dt;
    float ea = expf(dr);
    float ar = ea * cosf(di), ai = ea * sinf(di);
    float eT = expf(dr * 64.0f);
    cAT[idx * 2 + 0] = eT * cosf(di * 64.0f);
    cAT[idx * 2 + 1] = eT * sinf(di * 64.0f);
    float nr = ar - 1.0f, ni = ai;
    float inv = 1.0f / (Ar * Ar + Ai * Ai);
    float qr = (nr * Ar + ni * Ai) * inv;
    float qi = (ni * Ar - nr * Ai) * inv;
    float c2r = C2[idx * 2 + 0], c2i = C2[idx * 2 + 1];
    sdr[n] = dr; sdi[n] = di;
    sCr[n] = 2.0f * (c2r * qr - c2i * qi);
    sCi[n] = 2.0f * (c2r * qi + c2i * qr);
  }
  __syncthreads();
  {
    int n = tid >> 3, dq = tid & 7;
    float dr = sdr[n], di = sdi[n], Cr = sCr[n], Ci = sCi[n];
    float d0 = (float)(dq * 8);
    float e0 = expf(dr * d0);
    float pr = e0 * cosf(di * d0), pi = e0 * sinf(di * d0);
    float ea = expf(dr);
    float ar = ea * cosf(di), ai = ea * sinf(di);
#pragma unroll
    for (int j = 0; j < 8; j++) {
      tmp[n][dq * 8 + j] = Cr * pr - Ci * pi;
      float t = pr * ar - pi * ai;
      pi = pr * ai + pi * ar;
      pr = t;
    }
  }
  __syncthreads();
  {
    int d = tid & 63, q = tid >> 6;
    float s = 0.0f;
#pragma unroll
    for (int k = 0; k < 8; k++) s += tmp[q * 8 + k][d];
    part[q][d] = s;
  }
  __syncthreads();
  if (tid < 64) kt[tid] = part[0][tid] + part[1][tid] + part[2][tid] + part[3][tid];
  __syncthreads();
  // Lm
  {
    int row = tid >> 2, tq = (tid & 3) * 16;
    float Dh = Dp[lh];
    u16 vals[16];
    for (int j = 0; j < 16; j++) {
      int d = row - (tq + j);
      float v = 0.0f;
      if (d >= 0) { v = kt[d]; if (d == 0) v += Dh; }
      vals[j] = f2bf(v);
    }
    u16* dst = Lm + (size_t)lh * 4096 + row * 64 + tq;
    ushort8_t o0, o1;
    for (int j = 0; j < 8; j++) { o0[j] = vals[j]; o1[j] = vals[8 + j]; }
    *(ushort8_t*)dst = o0;
    *(ushort8_t*)(dst + 8) = o1;
  }
  // Em
  {
    int row = tid >> 2, tq = (tid & 3) * 16;
    int n = row >> 1, im = row & 1;
    float dr = sdr[n], di = sdi[n];
    float p0 = (float)(48 - tq);
    float e0 = expf(dr * p0);
    float pr = e0 * cosf(di * p0), pi = e0 * sinf(di * p0);
    float ea = expf(dr);
    float ar = ea * cosf(di), ai = ea * sinf(di);
    u16 vals[16];
#pragma unroll
    for (int j = 15; j >= 0; j--) {
      vals[j] = f2bf(im ? pi : pr);
      float t = pr * ar - pi * ai;
      pi = pr * ai + pi * ar;
      pr = t;
    }
    u16* dst = Em + (size_t)lh * 4096 + row * 64 + tq;
    ushort8_t o0, o1;
    for (int j = 0; j < 8; j++) { o0[j] = vals[j]; o1[j] = vals[8 + j]; }
    *(ushort8_t*)dst = o0;
    *(ushort8_t*)(dst + 8) = o1;
  }
  // Fm
  {
    int n2 = tid & 31, tg = tid >> 5;
    float dr = sdr[n2], di = sdi[n2], Cr = sCr[n2], Ci = sCi[n2];
    float p0 = (float)(tg * 8 + 1);
    float e0 = expf(dr * p0);
    float pr = e0 * cosf(di * p0), pi = e0 * sinf(di * p0);
    float ea = expf(dr);
    float ar = ea * cosf(di), ai = ea * sinf(di);
#pragma unroll
    for (int j = 0; j < 8; j++) {
      float wr = Cr * pr - Ci * pi;
      float wi = Cr * pi + Ci * pr;
      ushort2_t o; o[0] = f2bf(wr); o[1] = f2bf(-wi);
      *(ushort2_t*)(Fm + (size_t)lh * 4096 + (tg * 8 + j) * 64 + n2 * 2) = o;
      float t = pr * ar - pi * ai;
      pi = pr * ai + pi * ar;
      pr = t;
    }
  }
}

// ---- Wglu (l,o,k) fp32 -> Wf bf16 frag layout; 8 k per thread, coalesced 16B writes
__global__ void k_wf(const float* __restrict__ Wglu, u16* __restrict__ Wf) {
  int tid = blockIdx.x * 256 + threadIdx.x;   // 65536 threads
  int o15 = tid & 15;
  int kg  = (tid >> 4) & 31;
  int ot  = (tid >> 9) & 31;
  int l   = tid >> 14;
  int o = ot * 16 + o15;
  const float* src = Wglu + ((size_t)(l * 512 + o) * 256 + kg * 8);
  float4 f0 = *(const float4*)src;
  float4 f1 = *(const float4*)(src + 4);
  ushort8_t v;
  v[0] = f2bf(f0.x); v[1] = f2bf(f0.y); v[2] = f2bf(f0.z); v[3] = f2bf(f0.w);
  v[4] = f2bf(f1.x); v[5] = f2bf(f1.y); v[6] = f2bf(f1.z); v[7] = f2bf(f1.w);
  *(ushort8_t*)((char*)Wf + (size_t)l * 262144 + ot * 8192 + kg * 256 + o15 * 16) = v;
}

// ---- Win fp32 (182,256) -> Wt bf16 [h][192] -------------------------------------
__global__ void k_wtin(const float* __restrict__ Win, u16* __restrict__ Wt) {
  int idx = blockIdx.x * blockDim.x + threadIdx.x;
  if (idx >= Hn * KP) return;
  int h = idx / KP, k = idx - h * KP;
  Wt[idx] = (k < IN_DIM) ? f2bf(Win[(size_t)k * Hn + h]) : (u16)0;
}

// ---- input projection: 512 thr, 128 rows x all 256 h, XOR-swizzled 48KB A-tile --
__global__ __launch_bounds__(512) void k_inproj(const float* __restrict__ nin,
                                                const u16* __restrict__ Wt,
                                                const float* __restrict__ b_in,
                                                u16* __restrict__ Xc) {
  __shared__ __align__(16) u16 at[128 * 192];  // 48KB; byte = r*384 + ((kg^(r&7))<<4) + (k&7)*2
  int tid = threadIdx.x;
  int bx = blockIdx.x;   // 512
  int m0 = bx * 128;
  for (int i = tid; i < 128 * 10; i += 512) {
    int r = i / 10, k = IN_DIM + (i - r * 10);
    *(u16*)((char*)at + r * 384 + ((((k >> 3)) ^ (r & 7)) << 4) + (k & 7) * 2) = 0;
  }
  const float4* src = (const float4*)(nin + (size_t)m0 * IN_DIM);
  for (int i = tid; i < 128 * IN_DIM / 4; i += 512) {
    float4 v = src[i];
    int e0 = i * 4;
    int r = e0 / IN_DIM;
    int c = e0 - r * IN_DIM;
    float vv[4] = {v.x, v.y, v.z, v.w};
#pragma unroll
    for (int j = 0; j < 4; j++) {
      int rr = r, cc = c + j;
      if (cc >= IN_DIM) { rr++; cc -= IN_DIM; }
      *(u16*)((char*)at + rr * 384 + ((((cc >> 3)) ^ (rr & 7)) << 4) + (cc & 7) * 2) = f2bf(vv[j]);
    }
  }
  __syncthreads();
  int lane = tid & 63, wave = tid >> 6;
  int wm = wave >> 2, wn = wave & 3;
  int l15 = lane & 15, l4 = lane >> 4;
  int h0 = wn * 64;
  f32x4 acc[4][4] = {};
#pragma unroll
  for (int ks = 0; ks < 6; ks++) {
    int k0 = ks * 32 + l4 * 8;
    int kg = ks * 4 + l4;
    short8 a[4], bfr[4];
#pragma unroll
    for (int mt = 0; mt < 4; mt++) {
      int row = wm * 64 + mt * 16 + l15;
      a[mt] = *(const short8*)((const char*)at + row * 384 + ((kg ^ (row & 7)) << 4));
    }
#pragma unroll
    for (int nt = 0; nt < 4; nt++)
      bfr[nt] = *(const short8*)(Wt + (size_t)(h0 + nt * 16 + l15) * KP + k0);
#pragma unroll
    for (int mt = 0; mt < 4; mt++)
#pragma unroll
      for (int nt = 0; nt < 4; nt++)
        acc[mt][nt] = __builtin_amdgcn_mfma_f32_16x16x32_bf16(a[mt], bfr[nt], acc[mt][nt], 0, 0, 0);
  }
#pragma unroll
  for (int mt = 0; mt < 4; mt++) {
#pragma unroll
    for (int nt = 0; nt < 4; nt++) {
      int j = h0 + nt * 16 + l15;
      float bb = b_in[j];
      int r0 = m0 + wm * 64 + mt * 16 + l4 * 4;
      int b = r0 >> 11, li = r0 & 2047;
      int c = li >> 6, t0 = li & 63;
      ushort4_t w;
#pragma unroll
      for (int r = 0; r < 4; r++) w[r] = f2bf(acc[mt][nt][r] + bb);
      *(ushort4_t*)(Xc + ((size_t)(b * NCn + c) * Hn + j) * Tn + t0) = w;
    }
  }
}

// ---- fused S4D layer, 32KB LDS (ybuf overlays consumed sbuf half) ---------------
// sbuf slot(h,c) = (c>>4)*16384 + h*2048 + (c&15)*128; inner: 8 grp x 16B, XOR (c&7)
__global__ __launch_bounds__(512, 8) void k_s4d(const u16* __restrict__ Xc,
                                                const u16* __restrict__ Lm,
                                                const u16* __restrict__ Em,
                                                const u16* __restrict__ Fm,
                                                const float* __restrict__ cAT,
                                                u16* __restrict__ Gf, int layer) {
  __shared__ __align__(16) char sbuf[32768];
  int tid = threadIdx.x;
  int lane = tid & 63, w = tid >> 6;          // wave w owns h = hg*8 + w
  int l15 = lane & 15, l4 = lane >> 4;
  int flat = blockIdx.x;                      // 0..1023
  int vid = (flat & 7) * 128 + (flat >> 3);   // XCD-chunked bijection
  int hg = vid >> 5;
  int b = vid & 31;
  int h = hg * 8 + w;

  // phase A: load u-frags, E@U -> s_end LDS
  short8 ufr[2][2];   // [nt][ks]
  const u16* xb = Xc + ((size_t)(b * NCn) * Hn + h) * Tn;
#pragma unroll
  for (int nt = 0; nt < 2; nt++)
#pragma unroll
    for (int ks = 0; ks < 2; ks++)
      ufr[nt][ks] = *(const short8*)(xb + (size_t)(nt * 16 + l15) * (Hn * Tn) + ks * 32 + l4 * 8);
  const u16* eb = Em + (size_t)(layer * Hn + h) * 4096;
#pragma unroll
  for (int mt = 0; mt < 4; mt++) {
    f32x4 sacc[2] = {};
#pragma unroll
    for (int ks = 0; ks < 2; ks++) {
      short8 af = *(const short8*)(eb + (mt * 16 + l15) * 64 + ks * 32 + l4 * 8);
#pragma unroll
      for (int nt = 0; nt < 2; nt++)
        sacc[nt] = __builtin_amdgcn_mfma_f32_16x16x32_bf16(af, ufr[nt][ks], sacc[nt], 0, 0, 0);
    }
    int g = mt * 2 + (l4 >> 1), half = l4 & 1;
#pragma unroll
    for (int nt = 0; nt < 2; nt++) {
      int c = nt * 16 + l15;
      ushort4_t wv;
#pragma unroll
      for (int r = 0; r < 4; r++) wv[r] = f2bf(sacc[nt][r]);
      *(ushort4_t*)(sbuf + nt * 16384 + w * 2048 + l15 * 128 + ((g ^ (c & 7)) << 4) + half * 8) = wv;
    }
  }
  __syncthreads();
  // phase B: carry scan (256 threads; 4 passes of 8 chunks in regs)
  if (tid < 256) {
    int hl = tid >> 5, n = tid & 31;
    int hh = hg * 8 + hl;
    float aTr = cAT[((size_t)(layer * Hn + hh) * N2n + n) * 2 + 0];
    float aTi = cAT[((size_t)(layer * Hn + hh) * N2n + n) * 2 + 1];
    int grp = n >> 2, off = (n & 3) * 4;
    float cr = 0.0f, ci = 0.0f;
#pragma unroll
    for (int p = 0; p < 4; p++) {
      unsigned int sv[8];
#pragma unroll
      for (int q = 0; q < 8; q++) {
        int c = p * 8 + q;
        sv[q] = *(const unsigned int*)(sbuf + (c >> 4) * 16384 + hl * 2048 + (c & 15) * 128 +
                                       ((grp ^ (c & 7)) << 4) + off);
      }
#pragma unroll
      for (int q = 0; q < 8; q++) {
        unsigned int s = sv[q];
        float sre = bf2f((u16)(s & 0xffffu));
        float sim = bf2f((u16)(s >> 16));
        sv[q] = (unsigned int)f2bf(cr) | ((unsigned int)f2bf(ci) << 16);  // carry-IN
        float nr = aTr * cr - aTi * ci + sre;
        float ni = aTr * ci + aTi * cr + sim;
        cr = nr; ci = ni;
      }
#pragma unroll
      for (int q = 0; q < 8; q++) {
        int c = p * 8 + q;
        *(unsigned int*)(sbuf + (c >> 4) * 16384 + hl * 2048 + (c & 15) * 128 +
                         ((grp ^ (c & 7)) << 4) + off) = sv[q];
      }
    }
  }
  __syncthreads();
  // phase C/D: per nt half; ybuf overlays sbuf region nt after carry-frag hoist
  const u16* lb = Lm + (size_t)(layer * Hn + h) * 4096;
  const u16* fb = Fm + (size_t)(layer * Hn + h) * 4096;
  u16* gp = Gf + (size_t)(hg * Bn + b) * Ln * 8;
  for (int nt = 0; nt < 2; nt++) {
    int c = nt * 16 + l15;
    short8 cf[2];
#pragma unroll
    for (int ks = 0; ks < 2; ks++)
      cf[ks] = *(const short8*)(sbuf + nt * 16384 + w * 2048 + l15 * 128 +
                                (((ks * 4 + l4) ^ (c & 7)) << 4));
    __syncthreads();   // all carry reads complete before ybuf overlay writes
#pragma unroll
    for (int mt = 0; mt < 4; mt++) {
      f32x4 yacc = {};
#pragma unroll
      for (int ks = 0; ks < 2; ks++) {
        short8 af = *(const short8*)(lb + (mt * 16 + l15) * 64 + ks * 32 + l4 * 8);
        yacc = __builtin_amdgcn_mfma_f32_16x16x32_bf16(af, ufr[nt][ks], yacc, 0, 0, 0);
      }
#pragma unroll
      for (int ks = 0; ks < 2; ks++) {
        short8 af = *(const short8*)(fb + (mt * 16 + l15) * 64 + ks * 32 + l4 * 8);
        yacc = __builtin_amdgcn_mfma_f32_16x16x32_bf16(af, cf[ks], yacc, 0, 0, 0);
      }
      ushort4_t wv;
#pragma unroll
      for (int r = 0; r < 4; r++) {
        float y = yacc[r];
        wv[r] = f2bf(0.5f * y * (1.0f + erff(y * 0.70710678118654752f)));
      }
      int g = ((mt * 4 + l4) ^ l15) & 15;
      *(ushort4_t*)(sbuf + nt * 16384 + (l15 * 8 + w) * 128 + g * 8) = wv;
    }
    __syncthreads();
    // phase D half: 1024 m-rows, 512 threads x 2
#pragma unroll
    for (int it = 0; it < 2; it++) {
      int mloc = it * 512 + tid;
      int cl = mloc >> 6, t = mloc & 63;
      int g = ((t >> 2) ^ cl) & 15;
      const char* bb = sbuf + nt * 16384 + (cl * 8) * 128 + g * 8 + (t & 3) * 2;
      ushort8_t o;
#pragma unroll
      for (int hl = 0; hl < 8; hl++) o[hl] = *(const u16*)(bb + hl * 128);
      int m = (nt * 16 + cl) * 64 + t;
      *(ushort8_t*)(gp + (size_t)m * 8) = o;
    }
    __syncthreads();
  }
}

// ---- GLU via MFMA: 512 thr (2m x 4n waves), 128m x 256 out-pairs per block ------
template <int LAST>
__global__ __launch_bounds__(512) void k_glu(const u16* __restrict__ Gf,
                                             const u16* __restrict__ Wf,
                                             const float* __restrict__ bglu,
                                             u16* __restrict__ Xout, int layer) {
  int tid = threadIdx.x;
  int flat = blockIdx.x;                 // 0..1023
  int vid = (flat & 7) * 128 + (flat >> 3);
  int bx = vid >> 1;   // 512
  int nb2 = vid & 1;   // 2
  int lane = tid & 63, wave = tid >> 6;
  int wm = wave >> 2, wn = wave & 3;
  int l15 = lane & 15, l4 = lane >> 4;
  int m0 = bx * 128 + wm * 64;
  const char* wb = (const char*)Wf + (size_t)layer * 262144 + lane * 16;
  f32x4 acc[4][4] = {};
#pragma unroll 2
  for (int ks = 0; ks < 8; ks++) {
    short8 a[4], bfr[4];
#pragma unroll
    for (int rg = 0; rg < 4; rg++)
      a[rg] = *(const short8*)(Gf + (size_t)(ks * 4 + l4) * 524288 + (size_t)(m0 + rg * 16 + l15) * 8);
#pragma unroll
    for (int ct = 0; ct < 2; ct++) {
      int ot = nb2 * 8 + wn * 2 + ct;
      bfr[ct]     = *(const short8*)(wb + (size_t)ot * 8192 + ks * 1024);
      bfr[ct + 2] = *(const short8*)(wb + (size_t)(16 + ot) * 8192 + ks * 1024);
    }
#pragma unroll
    for (int rg = 0; rg < 4; rg++)
#pragma unroll
      for (int ct = 0; ct < 4; ct++)
        acc[rg][ct] = __builtin_amdgcn_mfma_f32_16x16x32_bf16(a[rg], bfr[ct], acc[rg][ct], 0, 0, 0);
  }
  int c0 = nb2 * 128 + wn * 32;
#pragma unroll
  for (int rg = 0; rg < 4; rg++) {
#pragma unroll
    for (int ct = 0; ct < 2; ct++) {
      int j = c0 + ct * 16 + l15;
      float ba = bglu[layer * 512 + j];
      float bg = bglu[layer * 512 + 256 + j];
      f32x4 va = acc[rg][ct], vg = acc[rg][ct + 2];
      int r0 = m0 + rg * 16 + l4 * 4;
      if (LAST) {
#pragma unroll
        for (int r = 0; r < 4; r++) {
          float za = va[r] + ba, zg = vg[r] + bg;
          Xout[(size_t)(r0 + r) * Hn + j] = f2bf(za / (1.0f + expf(-zg)));
        }
      } else {
        int b = r0 >> 11, li = r0 & 2047;
        int c = li >> 6, t0 = li & 63;
        ushort4_t w;
#pragma unroll
        for (int r = 0; r < 4; r++) {
          float za = va[r] + ba, zg = vg[r] + bg;
          w[r] = f2bf(za / (1.0f + expf(-zg)));
        }
        *(ushort4_t*)(Xout + ((size_t)(b * NCn + c) * Hn + j) * Tn + t0) = w;
      }
    }
  }
}

// ---- output projection: (B*L,256) bf16 @ (256,2) + b ----------------------------
__global__ __launch_bounds__(256) void k_outproj(const u16* __restrict__ Xp,
                                                 const float* __restrict__ Wout,
                                                 const float* __restrict__ b_out,
                                                 float* __restrict__ out) {
  int row = blockIdx.x * 4 + (threadIdx.x >> 6);
  int lane = threadIdx.x & 63;
  ushort4_t xv = *(const ushort4_t*)(Xp + (size_t)row * Hn + lane * 4);
  float x0 = bf2f(xv[0]), x1 = bf2f(xv[1]), x2 = bf2f(xv[2]), x3 = bf2f(xv[3]);
  const float4 w01 = *(const float4*)&Wout[lane * 8];
  const float4 w23 = *(const float4*)&Wout[lane * 8 + 4];
  float p0 = x0 * w01.x + x1 * w01.z + x2 * w23.x + x3 * w23.z;
  float p1 = x0 * w01.y + x1 * w01.w + x2 * w23.y + x3 * w23.w;
  for (int off = 32; off; off >>= 1) {
    p0 += __shfl_down(p0, off, 64);
    p1 += __shfl_down(p1, off, 64);
  }
  if (lane == 0) {
    out[(size_t)row * 2 + 0] = p0 + b_out[0];
    out[(size_t)row * 2 + 1] = p1 + b_out[1];
  }
}

extern "C" void kernel_launch(void* const* d_in, const int* in_sizes, int n_in,
                              void* d_out, int out_size, void* d_ws, size_t ws_size,
                              hipStream_t stream) {
  const float* nin        = (const float*)d_in[0];
  const float* Win        = (const float*)d_in[1];
  const float* b_in       = (const float*)d_in[2];
  const float* C2         = (const float*)d_in[3];
  const float* log_dt     = (const float*)d_in[4];
  const float* log_A_real = (const float*)d_in[5];
  const float* A_imag     = (const float*)d_in[6];
  const float* Dp         = (const float*)d_in[7];
  const float* Wglu       = (const float*)d_in[8];
  const float* bglu       = (const float*)d_in[9];
  const float* Wout       = (const float*)d_in[10];
  const float* b_out      = (const float*)d_in[11];
  float* out = (float*)d_out;

  u16* Xc = (u16*)d_ws;
  u16* Gf = Xc + (size_t)16777216;
  u16* Wt = Gf + (size_t)16777216;
  u16* Wf = Wt + (size_t)49152;
  u16* Lm = Wf + (size_t)524288;
  u16* Em = Lm + (size_t)4194304;
  u16* Fm = Em + (size_t)4194304;
  float* cAT = (float*)(Fm + (size_t)4194304);

  k_prep<<<NLn * Hn, 256, 0, stream>>>(C2, log_dt, log_A_real, A_imag, Dp, cAT, Lm, Em, Fm);
  k_wf<<<256, 256, 0, stream>>>(Wglu, Wf);
  k_wtin<<<(Hn * KP + 255) / 256, 256, 0, stream>>>(Win, Wt);
  k_inproj<<<512, 512, 0, stream>>>(nin, Wt, b_in, Xc);
  for (int l = 0; l < NLn; l++) {
    k_s4d<<<1024, 512, 0, stream>>>(Xc, Lm, Em, Fm, cAT, Gf, l);
    if (l < NLn - 1)
      k_glu<0><<<1024, 512, 0, stream>>>(Gf, Wf, bglu, Xc, l);
    else
      k_glu<1><<<1024, 512, 0, stream>>>(Gf, Wf, bglu, Xc, l);
  }
  k_outproj<<<Bn * Ln / 4, 256, 0, stream>>>(Xc, Wout, b_out, out);
}